// Round 1
// baseline (2767.559 us; speedup 1.0000x reference)
//
#include <hip/hip_runtime.h>

// LowRankAttention: B=2,H=12 (BH=24), S=8192, D=64, RANK=16, 10 steps, fp32.
#define S_ 8192
#define D_ 64
#define R_ 16
#define BH_ 24

// accumulator set layout per bh (floats):
#define ACC_RR 0        // RRraw[k][l]   = sum_i rp[k,i]^2 rp[l,i]^2      (256)
#define ACC_KR 256      // KRraw[l][a]   = sum_i key[i,a] rp[l,i]^2       (1024)
#define ACC_N  1280     // nrm2_rp[k]    = sum_i rp[k,i]^2                (16)
#define ACC_LL 1296     // LL[k][l]      = sum_j L[j,k] L[j,l]            (256)
#define ACC_LQ 1552     // LQ[k][a]      = sum_j L[j,k] q[j,a]            (1024)
#define ACC_PJ 2576     // proj[k]       = sum_i rs[k,i] dr2[k,i]         (16)
#define ACC_BH 2592
#define ACC_SET (BH_ * ACC_BH)   // 62208

static constexpr float INV_S2 = 1.0f / (8192.0f * 8192.0f);
static constexpr float STEPSZ = 1000.0f;

static __device__ __forceinline__ float warp_sum64(float v) {
#pragma unroll
  for (int m = 1; m < 64; m <<= 1) v += __shfl_xor(v, m);
  return v;
}

__global__ void k_zero(float* __restrict__ p, int n) {
  for (int i = blockIdx.x * blockDim.x + threadIdx.x; i < n; i += gridDim.x * blockDim.x)
    p[i] = 0.0f;
}

// one thread per row j: copy lp0 -> lp, write L = unit(lp)^2
__global__ void k_init_lp(const float* __restrict__ lp0, float* __restrict__ lp,
                          float* __restrict__ Lb) {
  int bh = blockIdx.y;
  int j = blockIdx.x * 256 + threadIdx.x;
  size_t base = ((size_t)bh * S_ + j) * R_;
  const float4* src = (const float4*)(lp0 + base);
  float4* dl = (float4*)(lp + base);
  float4* dL = (float4*)(Lb + base);
  float4 a[4];
#pragma unroll
  for (int u = 0; u < 4; ++u) a[u] = src[u];
  float n2 = 0.f;
#pragma unroll
  for (int u = 0; u < 4; ++u)
    n2 += a[u].x * a[u].x + a[u].y * a[u].y + a[u].z * a[u].z + a[u].w * a[u].w;
  float ri = rsqrtf(n2);
  float r2 = ri * ri;
#pragma unroll
  for (int u = 0; u < 4; ++u) {
    dl[u] = a[u];
    float4 L;
    L.x = a[u].x * a[u].x * r2; L.y = a[u].y * a[u].y * r2;
    L.z = a[u].z * a[u].z * r2; L.w = a[u].w * a[u].w * r2;
    dL[u] = L;
  }
}

// one thread per col i: copy rp0 -> rp, accumulate nrm2 into set0
__global__ void k_init_rp(const float* __restrict__ rp0, float* __restrict__ rp,
                          float* __restrict__ acc0) {
  int bh = blockIdx.y;
  int i = blockIdx.x * 256 + threadIdx.x;
  size_t base = (size_t)bh * R_ * S_ + i;
  float pn[16];
#pragma unroll
  for (int l = 0; l < 16; ++l) {
    float v = rp0[base + (size_t)l * S_];
    rp[base + (size_t)l * S_] = v;
    pn[l] = v * v;
  }
#pragma unroll
  for (int l = 0; l < 16; ++l) pn[l] = warp_sum64(pn[l]);
  if ((threadIdx.x & 63) == 0) {
    float* dst = acc0 + bh * ACC_BH + ACC_N;
#pragma unroll
    for (int l = 0; l < 16; ++l) atomicAdd(dst + l, pn[l]);
  }
}

// LL/LQ reduction: block 256 = (tc 0..15, tr 0..15), grid (16, BH)
__global__ void __launch_bounds__(256) k_red_L(const float* __restrict__ Lb,
                                               const float* __restrict__ q,
                                               float* __restrict__ accOut) {
  int bh = blockIdx.y;
  int t = threadIdx.x;
  int tc = t & 15, tr = t >> 4, wid = t >> 6;
  float acc[5][16];
#pragma unroll
  for (int u = 0; u < 5; ++u)
#pragma unroll
    for (int l = 0; l < 16; ++l) acc[u][l] = 0.f;
  const float* Lrow = Lb + (size_t)bh * S_ * R_;
  const float* qrow = q + (size_t)bh * S_ * D_;
  int j0 = blockIdx.x * 512;
  for (int it = 0; it < 32; ++it) {
    int j = j0 + tr + (it << 4);
    const float4* L4 = (const float4*)(Lrow + (size_t)j * R_);
    float4 a0 = L4[0], a1 = L4[1], a2 = L4[2], a3 = L4[3];
    float Lv[16] = {a0.x, a0.y, a0.z, a0.w, a1.x, a1.y, a1.z, a1.w,
                    a2.x, a2.y, a2.z, a2.w, a3.x, a3.y, a3.z, a3.w};
    float Lc = Lrow[(size_t)j * R_ + tc];
    float qv[4];
#pragma unroll
    for (int u = 0; u < 4; ++u) qv[u] = qrow[(size_t)j * D_ + tc + (u << 4)];
#pragma unroll
    for (int u = 0; u < 4; ++u)
#pragma unroll
      for (int l = 0; l < 16; ++l) acc[u][l] += Lv[l] * qv[u];
#pragma unroll
    for (int l = 0; l < 16; ++l) acc[4][l] += Lv[l] * Lc;
  }
#pragma unroll
  for (int u = 0; u < 5; ++u)
#pragma unroll
    for (int l = 0; l < 16; ++l) {
      float v = acc[u][l];
      v += __shfl_xor(v, 16);
      v += __shfl_xor(v, 32);
      acc[u][l] = v;
    }
  __shared__ float red[4 * 1280];
  if ((t & 63) < 16) {
#pragma unroll
    for (int u = 0; u < 5; ++u)
#pragma unroll
      for (int l = 0; l < 16; ++l) red[wid * 1280 + tc * 80 + u * 16 + l] = acc[u][l];
  }
  __syncthreads();
  for (int o = t; o < 1280; o += 256) {
    float s = red[o] + red[1280 + o] + red[2560 + o] + red[3840 + o];
    int tcc = o / 80, slot = o - tcc * 80;
    int u = slot >> 4, l = slot & 15;
    int idx = (u < 4) ? (ACC_LQ + l * 64 + tcc + (u << 4)) : (ACC_LL + l * 16 + tcc);
    atomicAdd(accOut + bh * ACC_BH + idx, s);
  }
}

// RRraw/KRraw reduction over columns i
__global__ void __launch_bounds__(256) k_red_R(const float* __restrict__ rp,
                                               const float* __restrict__ key,
                                               float* __restrict__ accOut) {
  int bh = blockIdx.y;
  int t = threadIdx.x;
  int tc = t & 15, tr = t >> 4, wid = t >> 6;
  float acc[5][16];
#pragma unroll
  for (int u = 0; u < 5; ++u)
#pragma unroll
    for (int l = 0; l < 16; ++l) acc[u][l] = 0.f;
  const float* rpb = rp + (size_t)bh * R_ * S_;
  const float* kb = key + (size_t)bh * S_ * D_;
  int i0 = blockIdx.x * 512;
  for (int it = 0; it < 32; ++it) {
    int i = i0 + tr + (it << 4);
    float rv[16];
#pragma unroll
    for (int l = 0; l < 16; ++l) {
      float x = rpb[(size_t)l * S_ + i];
      rv[l] = x * x;
    }
    float rc = rpb[(size_t)tc * S_ + i];
    rc = rc * rc;
    float kv[4];
#pragma unroll
    for (int u = 0; u < 4; ++u) kv[u] = kb[(size_t)i * D_ + tc + (u << 4)];
#pragma unroll
    for (int u = 0; u < 4; ++u)
#pragma unroll
      for (int l = 0; l < 16; ++l) acc[u][l] += rv[l] * kv[u];
#pragma unroll
    for (int l = 0; l < 16; ++l) acc[4][l] += rv[l] * rc;
  }
#pragma unroll
  for (int u = 0; u < 5; ++u)
#pragma unroll
    for (int l = 0; l < 16; ++l) {
      float v = acc[u][l];
      v += __shfl_xor(v, 16);
      v += __shfl_xor(v, 32);
      acc[u][l] = v;
    }
  __shared__ float red[4 * 1280];
  if ((t & 63) < 16) {
#pragma unroll
    for (int u = 0; u < 5; ++u)
#pragma unroll
      for (int l = 0; l < 16; ++l) red[wid * 1280 + tc * 80 + u * 16 + l] = acc[u][l];
  }
  __syncthreads();
  for (int o = t; o < 1280; o += 256) {
    float s = red[o] + red[1280 + o] + red[2560 + o] + red[3840 + o];
    int tcc = o / 80, slot = o - tcc * 80;
    int u = slot >> 4, l = slot & 15;
    int idx = (u < 4) ? (ACC_KR + l * 64 + tcc + (u << 4)) : (ACC_RR + l * 16 + tcc);
    atomicAdd(accOut + bh * ACC_BH + idx, s);
  }
}

// final rv_raw[k][d] = sum_i rp[k,i]^2 v[i,d]
__global__ void __launch_bounds__(256) k_rv(const float* __restrict__ rp,
                                            const float* __restrict__ vv,
                                            float* __restrict__ rvout) {
  int bh = blockIdx.y;
  int t = threadIdx.x;
  int tc = t & 15, tr = t >> 4, wid = t >> 6;
  float acc[4][16];
#pragma unroll
  for (int u = 0; u < 4; ++u)
#pragma unroll
    for (int l = 0; l < 16; ++l) acc[u][l] = 0.f;
  const float* rpb = rp + (size_t)bh * R_ * S_;
  const float* vb = vv + (size_t)bh * S_ * D_;
  int i0 = blockIdx.x * 512;
  for (int it = 0; it < 32; ++it) {
    int i = i0 + tr + (it << 4);
    float rv[16];
#pragma unroll
    for (int l = 0; l < 16; ++l) {
      float x = rpb[(size_t)l * S_ + i];
      rv[l] = x * x;
    }
    float kv[4];
#pragma unroll
    for (int u = 0; u < 4; ++u) kv[u] = vb[(size_t)i * D_ + tc + (u << 4)];
#pragma unroll
    for (int u = 0; u < 4; ++u)
#pragma unroll
      for (int l = 0; l < 16; ++l) acc[u][l] += rv[l] * kv[u];
  }
#pragma unroll
  for (int u = 0; u < 4; ++u)
#pragma unroll
    for (int l = 0; l < 16; ++l) {
      float v = acc[u][l];
      v += __shfl_xor(v, 16);
      v += __shfl_xor(v, 32);
      acc[u][l] = v;
    }
  __shared__ float red[4 * 1024];
  if ((t & 63) < 16) {
#pragma unroll
    for (int u = 0; u < 4; ++u)
#pragma unroll
      for (int l = 0; l < 16; ++l) red[wid * 1024 + tc * 64 + u * 16 + l] = acc[u][l];
  }
  __syncthreads();
  for (int o = t; o < 1024; o += 256) {
    float s = red[o] + red[1024 + o] + red[2048 + o] + red[3072 + o];
    int tcc = o >> 6, slot = o & 63;
    int u = slot >> 4, l = slot & 15;
    atomicAdd(rvout + bh * 1024 + l * 64 + tcc + (u << 4), s);
  }
}

// per-row lp update + write L_new; one thread per row
__global__ void __launch_bounds__(256) k_row(const float* __restrict__ accS,
                                             const float* __restrict__ q,
                                             float* __restrict__ lp,
                                             float* __restrict__ Lb) {
  int bh = blockIdx.y;
  int t = threadIdx.x;
  __shared__ float innrm[16];
  __shared__ float RRs[256];    // [k][l] * 2*inv_s2 / (n_k n_l)
  __shared__ float KRts[1024];  // [a][l] = KR[l][a] * 2*inv_s2 / n_l
  const float* A = accS + bh * ACC_BH;
  if (t < 16) innrm[t] = 1.0f / A[ACC_N + t];
  __syncthreads();
  {
    int k = t >> 4, l = t & 15;
    RRs[t] = A[ACC_RR + t] * (2.0f * INV_S2) * innrm[k] * innrm[l];
  }
#pragma unroll
  for (int e = t; e < 1024; e += 256) {
    int a = e >> 4, l = e & 15;
    KRts[e] = A[ACC_KR + l * 64 + a] * (2.0f * INV_S2) * innrm[l];
  }
  __syncthreads();

  int j = blockIdx.x * 256 + t;
  size_t base = ((size_t)bh * S_ + j) * R_;
  float4* lp4 = (float4*)(lp + base);
  float4 a0 = lp4[0], a1 = lp4[1], a2 = lp4[2], a3 = lp4[3];
  float lv[16] = {a0.x, a0.y, a0.z, a0.w, a1.x, a1.y, a1.z, a1.w,
                  a2.x, a2.y, a2.z, a2.w, a3.x, a3.y, a3.z, a3.w};
  float n2 = 0.f;
#pragma unroll
  for (int l = 0; l < 16; ++l) n2 += lv[l] * lv[l];
  float ri = rsqrtf(n2);
  float ls[16], L[16];
#pragma unroll
  for (int l = 0; l < 16; ++l) {
    ls[l] = lv[l] * ri;
    L[l] = ls[l] * ls[l];
  }
  float dl[16];
#pragma unroll
  for (int l = 0; l < 16; ++l) dl[l] = 0.f;
  const float4* RR4 = (const float4*)RRs;
#pragma unroll
  for (int k = 0; k < 16; ++k) {
    float Lk = L[k];
#pragma unroll
    for (int g = 0; g < 4; ++g) {
      float4 rr = RR4[k * 4 + g];
      dl[4 * g + 0] += Lk * rr.x; dl[4 * g + 1] += Lk * rr.y;
      dl[4 * g + 2] += Lk * rr.z; dl[4 * g + 3] += Lk * rr.w;
    }
  }
  const float4* q4 = (const float4*)(q + ((size_t)bh * S_ + j) * D_);
  const float4* KR4 = (const float4*)KRts;
#pragma unroll
  for (int a4 = 0; a4 < 16; ++a4) {
    float4 qq = q4[a4];
#pragma unroll
    for (int c = 0; c < 4; ++c) {
      float qa = (c == 0) ? qq.x : (c == 1) ? qq.y : (c == 2) ? qq.z : qq.w;
      int a = a4 * 4 + c;
#pragma unroll
      for (int g = 0; g < 4; ++g) {
        float4 kr = KR4[a * 4 + g];
        dl[4 * g + 0] -= qa * kr.x; dl[4 * g + 1] -= qa * kr.y;
        dl[4 * g + 2] -= qa * kr.z; dl[4 * g + 3] -= qa * kr.w;
      }
    }
  }
  float dot = 0.f;
#pragma unroll
  for (int l = 0; l < 16; ++l) {
    dl[l] *= ls[l];
    dot += ls[l] * dl[l];
  }
#pragma unroll
  for (int l = 0; l < 16; ++l) {
    float d = (dl[l] - ls[l] * dot) * ri;
    lv[l] -= STEPSZ * d;
  }
  float4 o0 = {lv[0], lv[1], lv[2], lv[3]}, o1 = {lv[4], lv[5], lv[6], lv[7]};
  float4 o2 = {lv[8], lv[9], lv[10], lv[11]}, o3 = {lv[12], lv[13], lv[14], lv[15]};
  lp4[0] = o0; lp4[1] = o1; lp4[2] = o2; lp4[3] = o3;
  float m2 = 0.f;
#pragma unroll
  for (int l = 0; l < 16; ++l) m2 += lv[l] * lv[l];
  float ri2 = rsqrtf(m2);
  float rr2 = ri2 * ri2;
  float4* L4o = (float4*)(Lb + base);
  float4 L0 = {lv[0] * lv[0] * rr2, lv[1] * lv[1] * rr2, lv[2] * lv[2] * rr2, lv[3] * lv[3] * rr2};
  float4 L1 = {lv[4] * lv[4] * rr2, lv[5] * lv[5] * rr2, lv[6] * lv[6] * rr2, lv[7] * lv[7] * rr2};
  float4 L2 = {lv[8] * lv[8] * rr2, lv[9] * lv[9] * rr2, lv[10] * lv[10] * rr2, lv[11] * lv[11] * rr2};
  float4 L3 = {lv[12] * lv[12] * rr2, lv[13] * lv[13] * rr2, lv[14] * lv[14] * rr2, lv[15] * lv[15] * rr2};
  L4o[0] = L0; L4o[1] = L1; L4o[2] = L2; L4o[3] = L3;
}

// per-column dr2 + proj; one thread per column i
__global__ void __launch_bounds__(256) k_col(float* __restrict__ accS,
                                             const float* __restrict__ key,
                                             const float* __restrict__ rp,
                                             float* __restrict__ dr2) {
  int bh = blockIdx.y;
  int t = threadIdx.x;
  __shared__ float sInn[16], sRn[16];
  __shared__ float MLL[256];   // [k][l] = LL * 2*inv_s2 / n_l
  __shared__ float MLQ[1024];  // [k][a] = LQ * 2*inv_s2
  float* A = accS + bh * ACC_BH;
  if (t < 16) {
    float n2 = A[ACC_N + t];
    sInn[t] = 1.0f / n2;
    sRn[t] = rsqrtf(n2);
  }
  __syncthreads();
  {
    int l = t & 15;
    MLL[t] = A[ACC_LL + t] * (2.0f * INV_S2) * sInn[l];
  }
#pragma unroll
  for (int e = t; e < 1024; e += 256) MLQ[e] = A[ACC_LQ + e] * (2.0f * INV_S2);
  __syncthreads();

  int i = blockIdx.x * 256 + t;
  size_t cbase = (size_t)bh * R_ * S_ + i;
  float rv[16], rp2[16];
#pragma unroll
  for (int l = 0; l < 16; ++l) {
    float x = rp[cbase + (size_t)l * S_];
    rv[l] = x;
    rp2[l] = x * x;
  }
  const float4* k4 = (const float4*)(key + ((size_t)bh * S_ + i) * D_);
  float kv[64];
#pragma unroll
  for (int a4 = 0; a4 < 16; ++a4) {
    float4 x = k4[a4];
    kv[4 * a4 + 0] = x.x; kv[4 * a4 + 1] = x.y; kv[4 * a4 + 2] = x.z; kv[4 * a4 + 3] = x.w;
  }
  float pj[16];
  const float4* MLL4 = (const float4*)MLL;
  const float4* MLQ4 = (const float4*)MLQ;
#pragma unroll
  for (int k = 0; k < 16; ++k) {
    float s = 0.f;
#pragma unroll
    for (int g = 0; g < 4; ++g) {
      float4 m = MLL4[k * 4 + g];
      s += m.x * rp2[4 * g + 0] + m.y * rp2[4 * g + 1] + m.z * rp2[4 * g + 2] + m.w * rp2[4 * g + 3];
    }
#pragma unroll
    for (int a4 = 0; a4 < 16; ++a4) {
      float4 m = MLQ4[k * 16 + a4];
      s -= m.x * kv[4 * a4 + 0] + m.y * kv[4 * a4 + 1] + m.z * kv[4 * a4 + 2] + m.w * kv[4 * a4 + 3];
    }
    float rs = rv[k] * sRn[k];
    float d2 = rs * s;
    dr2[cbase + (size_t)k * S_] = d2;
    pj[k] = rs * d2;
  }
#pragma unroll
  for (int k = 0; k < 16; ++k) pj[k] = warp_sum64(pj[k]);
  if ((t & 63) == 0) {
    float* dst = A + ACC_PJ;
#pragma unroll
    for (int k = 0; k < 16; ++k) atomicAdd(dst + k, pj[k]);
  }
}

// rp update: rp_new = c1[k]*rp - c2[k]*dr2 ; accumulate next nrm2
__global__ void __launch_bounds__(256) k_col2(const float* __restrict__ accS,
                                              float* __restrict__ ntgt, int nstride,
                                              const float* __restrict__ dr2,
                                              float* __restrict__ rp) {
  int bh = blockIdx.y;
  int t = threadIdx.x;
  __shared__ float c1[16], c2[16];
  const float* A = accS + bh * ACC_BH;
  if (t < 16) {
    float n2 = A[ACC_N + t];
    float pjv = A[ACC_PJ + t];
    c1[t] = 1.0f + STEPSZ * pjv / n2;
    c2[t] = STEPSZ * rsqrtf(n2);
  }
  __syncthreads();
  int i = blockIdx.x * 256 + t;
  size_t cbase = (size_t)bh * R_ * S_ + i;
  float pn[16];
#pragma unroll
  for (int k = 0; k < 16; ++k) {
    float v = rp[cbase + (size_t)k * S_];
    float d = dr2[cbase + (size_t)k * S_];
    float nv = c1[k] * v - c2[k] * d;
    rp[cbase + (size_t)k * S_] = nv;
    pn[k] = nv * nv;
  }
#pragma unroll
  for (int k = 0; k < 16; ++k) pn[k] = warp_sum64(pn[k]);
  if ((t & 63) == 0) {
#pragma unroll
    for (int k = 0; k < 16; ++k) atomicAdd(ntgt + bh * nstride + k, pn[k]);
  }
}

// out[j][d] = sum_k unit(lp_j)^2[k] * rv[k][d]/nrm2f[k]
__global__ void __launch_bounds__(256) k_out(const float* __restrict__ lp,
                                             const float* __restrict__ rvraw,
                                             const float* __restrict__ nrm2f,
                                             float* __restrict__ out) {
  int bh = blockIdx.y;
  int t = threadIdx.x;
  __shared__ float sn[16];
  __shared__ float rvs[1024];
  if (t < 16) sn[t] = 1.0f / nrm2f[bh * 16 + t];
  __syncthreads();
#pragma unroll
  for (int e = t; e < 1024; e += 256) rvs[e] = rvraw[bh * 1024 + e] * sn[e >> 6];
  __syncthreads();
  int j = blockIdx.x * 256 + t;
  size_t base = ((size_t)bh * S_ + j) * R_;
  const float4* lp4 = (const float4*)(lp + base);
  float4 a0 = lp4[0], a1 = lp4[1], a2 = lp4[2], a3 = lp4[3];
  float lv[16] = {a0.x, a0.y, a0.z, a0.w, a1.x, a1.y, a1.z, a1.w,
                  a2.x, a2.y, a2.z, a2.w, a3.x, a3.y, a3.z, a3.w};
  float n2 = 0.f;
#pragma unroll
  for (int l = 0; l < 16; ++l) n2 += lv[l] * lv[l];
  float ri = rsqrtf(n2);
  float r2 = ri * ri;
  float L[16];
#pragma unroll
  for (int l = 0; l < 16; ++l) L[l] = lv[l] * lv[l] * r2;
  float o[64];
#pragma unroll
  for (int d = 0; d < 64; ++d) o[d] = 0.f;
  const float4* rv4 = (const float4*)rvs;
#pragma unroll
  for (int k = 0; k < 16; ++k) {
    float Lk = L[k];
#pragma unroll
    for (int d4 = 0; d4 < 16; ++d4) {
      float4 r = rv4[k * 16 + d4];
      o[4 * d4 + 0] += Lk * r.x; o[4 * d4 + 1] += Lk * r.y;
      o[4 * d4 + 2] += Lk * r.z; o[4 * d4 + 3] += Lk * r.w;
    }
  }
  float4* o4 = (float4*)(out + ((size_t)bh * S_ + j) * D_);
#pragma unroll
  for (int d4 = 0; d4 < 16; ++d4) {
    float4 w = {o[4 * d4 + 0], o[4 * d4 + 1], o[4 * d4 + 2], o[4 * d4 + 3]};
    o4[d4] = w;
  }
}

extern "C" void kernel_launch(void* const* d_in, const int* in_sizes, int n_in,
                              void* d_out, int out_size, void* d_ws, size_t ws_size,
                              hipStream_t stream) {
  (void)in_sizes; (void)n_in; (void)out_size; (void)ws_size;
  const float* q = (const float*)d_in[0];
  const float* key = (const float*)d_in[1];
  const float* v = (const float*)d_in[2];
  const float* lp0 = (const float*)d_in[3];
  const float* rp0 = (const float*)d_in[4];
  float* out = (float*)d_out;
  float* ws = (float*)d_ws;

  float* lp = ws;                       // 3,145,728 floats
  float* rp = lp + 3145728;             // 3,145,728
  float* Ldr = rp + 3145728;            // 3,145,728 (shared: L rows, then dr2)
  float* acc = Ldr + 3145728;           // 10 * ACC_SET = 622,080
  float* rv = acc + 10 * ACC_SET;       // 24,576
  float* nrm2f = rv + 24576;            // 384
  // total 10,084,224 floats = 40.3 MB of d_ws

  dim3 blk(256);
  dim3 g32(32, BH_), g16(16, BH_);
  int nzero = 10 * ACC_SET + 24576 + 384;
  k_zero<<<dim3(1024), blk, 0, stream>>>(acc, nzero);
  k_init_lp<<<g32, blk, 0, stream>>>(lp0, lp, Ldr);
  k_init_rp<<<g32, blk, 0, stream>>>(rp0, rp, acc);
  k_red_L<<<g16, blk, 0, stream>>>(Ldr, q, acc);
  k_red_R<<<g16, blk, 0, stream>>>(rp, key, acc);
  for (int s = 0; s < 10; ++s) {
    float* As = acc + s * ACC_SET;
    float* An = acc + (s + 1) * ACC_SET;
    k_row<<<g32, blk, 0, stream>>>(As, q, lp, Ldr);
    if (s < 9) k_red_L<<<g16, blk, 0, stream>>>(Ldr, q, An);
    k_col<<<g32, blk, 0, stream>>>(As, key, rp, Ldr);
    if (s < 9) {
      k_col2<<<g32, blk, 0, stream>>>(As, An + ACC_N, ACC_BH, Ldr, rp);
      k_red_R<<<g16, blk, 0, stream>>>(rp, key, An);
    } else {
      k_col2<<<g32, blk, 0, stream>>>(As, nrm2f, 16, Ldr, rp);
    }
  }
  k_rv<<<g16, blk, 0, stream>>>(rp, v, rv);
  k_out<<<g32, blk, 0, stream>>>(lp, rv, nrm2f, out);
}

// Round 2
// 1218.366 us; speedup vs baseline: 2.2715x; 2.2715x over previous
//
#include <hip/hip_runtime.h>

// LowRankAttention: B=2,H=12 (BH=24), S=8192, D=64, RANK=16, 10 steps, fp32.
#define S_ 8192
#define D_ 64
#define R_ 16
#define BH_ 24

static constexpr float INV_S2 = 1.0f / (8192.0f * 8192.0f);
static constexpr float STEPSZ = 1000.0f;
static constexpr float CC = 2.0f * INV_S2;

#define LP_N (BH_ * S_ * R_)          // 3,145,728 floats
#define PART_STRIDE 2576              // L:0..1279, R:1280..2559, N:2560..2575
#define PART_N (BH_ * 32 * PART_STRIDE)
#define ACCF_STRIDE 2624              // MLL 0, MLQ 256, RRS 1280, KRT 1536, C1 2560, C2 2576, SRN 2592, INN 2608
#define ACCF_N (BH_ * ACCF_STRIDE)
#define PART2_STRIDE 1040             // RV:0..1023, N:1024..1039
#define RVS_N (BH_ * 1024)

// ---------------------------------------------------------------------------
// kA: per-block partial reductions.  Block (bx,bh) covers 256 rows & 256 cols.
//   L-side: LL[k][l], LQ[k][a]   (from L=unit(lp)^2 and q)
//   R-side: RR[k][l], KR[l][a], N[k]  (from rp^2 and key)
// Partials written to part[(bh*32+bx)*2576 + ...], no atomics.
// ---------------------------------------------------------------------------
__global__ void __launch_bounds__(256) kA(const float* __restrict__ lp_src,
                                          const float* __restrict__ rp_src,
                                          const float* __restrict__ q,
                                          const float* __restrict__ key,
                                          float* __restrict__ part) {
  const int bh = blockIdx.y, bx = blockIdx.x, t = threadIdx.x;
  const int tc = t & 15, trw = t >> 4, w = t >> 6;
  __shared__ float lds[6144];   // stage[256][16] (16KB) / red[4][16][96] (24KB), time-shared
  const int j0 = bx * 256;

  // ---- stage L = unit(lp)^2 for this block's 256 rows ----
  {
    size_t base = ((size_t)bh * S_ + j0 + t) * R_;
    const float4* s4 = (const float4*)(lp_src + base);
    float4 a0 = s4[0], a1 = s4[1], a2 = s4[2], a3 = s4[3];
    float n2 = a0.x*a0.x + a0.y*a0.y + a0.z*a0.z + a0.w*a0.w
             + a1.x*a1.x + a1.y*a1.y + a1.z*a1.z + a1.w*a1.w
             + a2.x*a2.x + a2.y*a2.y + a2.z*a2.z + a2.w*a2.w
             + a3.x*a3.x + a3.y*a3.y + a3.z*a3.z + a3.w*a3.w;
    float r2 = 1.0f / n2;
    float4* st = (float4*)(lds + t * 16);
    st[0] = make_float4(a0.x*a0.x*r2, a0.y*a0.y*r2, a0.z*a0.z*r2, a0.w*a0.w*r2);
    st[1] = make_float4(a1.x*a1.x*r2, a1.y*a1.y*r2, a1.z*a1.z*r2, a1.w*a1.w*r2);
    st[2] = make_float4(a2.x*a2.x*r2, a2.y*a2.y*r2, a2.z*a2.z*r2, a2.w*a2.w*r2);
    st[3] = make_float4(a3.x*a3.x*r2, a3.y*a3.y*r2, a3.z*a3.z*r2, a3.w*a3.w*r2);
  }
  __syncthreads();

  float acc[5][16];
#pragma unroll
  for (int u = 0; u < 5; ++u)
#pragma unroll
    for (int l = 0; l < 16; ++l) acc[u][l] = 0.f;

  const float* qb = q + (size_t)bh * S_ * D_;
  for (int it = 0; it < 16; ++it) {
    int jl = trw + (it << 4);
    const float4* L4 = (const float4*)(lds + jl * 16);
    float4 b0 = L4[0], b1 = L4[1], b2 = L4[2], b3 = L4[3];
    float Lv[16] = {b0.x, b0.y, b0.z, b0.w, b1.x, b1.y, b1.z, b1.w,
                    b2.x, b2.y, b2.z, b2.w, b3.x, b3.y, b3.z, b3.w};
    float Lc = lds[jl * 16 + tc];
    float qv[4];
#pragma unroll
    for (int u = 0; u < 4; ++u) qv[u] = qb[(size_t)(j0 + jl) * D_ + tc + (u << 4)];
#pragma unroll
    for (int u = 0; u < 4; ++u)
#pragma unroll
      for (int l = 0; l < 16; ++l) acc[u][l] += Lv[l] * qv[u];   // LQ[l][tc+16u]
#pragma unroll
    for (int l = 0; l < 16; ++l) acc[4][l] += Lv[l] * Lc;        // LL[l][tc]
  }
#pragma unroll
  for (int u = 0; u < 5; ++u)
#pragma unroll
    for (int l = 0; l < 16; ++l) {
      float v = acc[u][l];
      v += __shfl_xor(v, 16);
      v += __shfl_xor(v, 32);
      acc[u][l] = v;
    }
  __syncthreads();   // stage reads done; overlay red
  if ((t & 63) < 16) {
#pragma unroll
    for (int u = 0; u < 5; ++u)
#pragma unroll
      for (int l = 0; l < 16; ++l) lds[w * 1536 + tc * 96 + u * 16 + l] = acc[u][l];
  }
  __syncthreads();
  float* pb = part + (size_t)(bh * 32 + bx) * PART_STRIDE;
#pragma unroll
  for (int r = 0; r < 5; ++r) {
    int o = t + r * 256;
    int sl = o >> 4, c = o & 15;
    pb[o] = lds[c * 96 + sl] + lds[1536 + c * 96 + sl] +
            lds[3072 + c * 96 + sl] + lds[4608 + c * 96 + sl];
  }
  __syncthreads();

  // ---- stage rp^2 for this block's 256 cols ----
  {
    size_t cb = (size_t)bh * R_ * S_ + j0 + t;
    float* st = lds + t * 16;
#pragma unroll
    for (int l = 0; l < 16; ++l) {
      float x = rp_src[cb + (size_t)l * S_];
      st[l] = x * x;
    }
  }
  __syncthreads();

  float accN[16];
#pragma unroll
  for (int u = 0; u < 5; ++u)
#pragma unroll
    for (int l = 0; l < 16; ++l) acc[u][l] = 0.f;
#pragma unroll
  for (int l = 0; l < 16; ++l) accN[l] = 0.f;

  const float* kb = key + (size_t)bh * S_ * D_;
  for (int it = 0; it < 16; ++it) {
    int jl = trw + (it << 4);
    const float4* R4 = (const float4*)(lds + jl * 16);
    float4 b0 = R4[0], b1 = R4[1], b2 = R4[2], b3 = R4[3];
    float rv[16] = {b0.x, b0.y, b0.z, b0.w, b1.x, b1.y, b1.z, b1.w,
                    b2.x, b2.y, b2.z, b2.w, b3.x, b3.y, b3.z, b3.w};
    float rc = lds[jl * 16 + tc];
    float kv[4];
#pragma unroll
    for (int u = 0; u < 4; ++u) kv[u] = kb[(size_t)(j0 + jl) * D_ + tc + (u << 4)];
#pragma unroll
    for (int u = 0; u < 4; ++u)
#pragma unroll
      for (int l = 0; l < 16; ++l) acc[u][l] += rv[l] * kv[u];   // KR[l][tc+16u]
#pragma unroll
    for (int l = 0; l < 16; ++l) acc[4][l] += rv[l] * rc;        // RR[l][tc]
#pragma unroll
    for (int l = 0; l < 16; ++l) accN[l] += rv[l];               // N[l] (tc-dup)
  }
#pragma unroll
  for (int u = 0; u < 5; ++u)
#pragma unroll
    for (int l = 0; l < 16; ++l) {
      float v = acc[u][l];
      v += __shfl_xor(v, 16);
      v += __shfl_xor(v, 32);
      acc[u][l] = v;
    }
#pragma unroll
  for (int l = 0; l < 16; ++l) {
    float v = accN[l];
    v += __shfl_xor(v, 16);
    v += __shfl_xor(v, 32);
    accN[l] = v;
  }
  __syncthreads();
  if ((t & 63) < 16) {
#pragma unroll
    for (int u = 0; u < 5; ++u)
#pragma unroll
      for (int l = 0; l < 16; ++l) lds[w * 1536 + tc * 96 + u * 16 + l] = acc[u][l];
    if (tc == 0) {
#pragma unroll
      for (int l = 0; l < 16; ++l) lds[w * 1536 + 80 + l] = accN[l];
    }
  }
  __syncthreads();
#pragma unroll
  for (int r = 0; r < 5; ++r) {
    int o = t + r * 256;
    int sl = o >> 4, c = o & 15;
    pb[1280 + o] = lds[c * 96 + sl] + lds[1536 + c * 96 + sl] +
                   lds[3072 + c * 96 + sl] + lds[4608 + c * 96 + sl];
  }
  if (t < 16)
    pb[2560 + t] = lds[80 + t] + lds[1536 + 80 + t] + lds[3072 + 80 + t] + lds[4608 + 80 + t];
}

// ---------------------------------------------------------------------------
// kB: one block per bh. Sum 32 partials, build all scaled matrices + analytic
// PJ + rp-update coefficients c1/c2.  PJ[k] = inn_k*(Σ_l MLL·RRraw − Σ_a MLQ·KRraw)
// ---------------------------------------------------------------------------
__global__ void __launch_bounds__(256) kB(const float* __restrict__ part,
                                          float* __restrict__ accF) {
  const int bh = blockIdx.x, t = threadIdx.x;
  __shared__ float raw[PART_STRIDE];
  __shared__ float inn[16], srn[16];
  const float* p0 = part + (size_t)bh * 32 * PART_STRIDE;
  for (int v = t; v < PART_STRIDE; v += 256) {
    float s = 0.f;
    const float* p = p0 + v;
#pragma unroll 8
    for (int b = 0; b < 32; ++b) s += p[(size_t)b * PART_STRIDE];
    raw[v] = s;
  }
  __syncthreads();
  if (t < 16) {
    float N = raw[2560 + t];
    inn[t] = 1.0f / N;
    srn[t] = rsqrtf(N);
  }
  __syncthreads();
  float* out = accF + (size_t)bh * ACCF_STRIDE;
  {  // MLL + RRS (256 each)
    int k = t >> 4, l = t & 15;
    float LLr = raw[(64 + k) * 16 + l];
    out[k * 16 + l] = LLr * CC * inn[l];                      // MLL[k][l]
    float RRr = raw[1280 + (64 + k) * 16 + l];
    out[1280 + k * 16 + l] = RRr * CC * inn[k] * inn[l];      // RRS[k][l]
  }
#pragma unroll
  for (int r = 0; r < 4; ++r) {  // MLQ[k*64+a]
    int e = t + r * 256;
    int k = e >> 6, a = e & 63, u = a >> 4, c = a & 15;
    out[256 + e] = raw[(u * 16 + k) * 16 + c] * CC;
  }
#pragma unroll
  for (int r = 0; r < 4; ++r) {  // KRT[a*16+l] = KRraw[l][a]*CC*inn[l]
    int e = t + r * 256;
    int a = e >> 4, l = e & 15, u = a >> 4, c = a & 15;
    out[1536 + e] = raw[1280 + (u * 16 + l) * 16 + c] * CC * inn[l];
  }
  if (t < 16) {
    int k = t;
    float s = 0.f;
#pragma unroll
    for (int l = 0; l < 16; ++l)
      s += raw[(64 + k) * 16 + l] * CC * inn[l] * raw[1280 + (64 + k) * 16 + l];
#pragma unroll
    for (int a = 0; a < 64; ++a) {
      int u = a >> 4, c = a & 15;
      s -= raw[(u * 16 + k) * 16 + c] * CC * raw[1280 + (u * 16 + k) * 16 + c];
    }
    float PJ = inn[k] * s;
    out[2560 + t] = 1.0f + STEPSZ * PJ * inn[t];   // c1
    out[2576 + t] = STEPSZ * srn[t];               // c2
    out[2592 + t] = srn[t];
    out[2608 + t] = inn[t];
  }
}

// ---------------------------------------------------------------------------
// kC: fused row (lp) + column (rp) update, fully thread-local, no atomics.
// ---------------------------------------------------------------------------
__global__ void __launch_bounds__(256) kC(const float* __restrict__ accF,
                                          const float* __restrict__ q,
                                          const float* __restrict__ key,
                                          const float* __restrict__ lp_src,
                                          const float* __restrict__ rp_src,
                                          float* __restrict__ lp_dst,
                                          float* __restrict__ rp_dst) {
  const int bh = blockIdx.y, t = threadIdx.x;
  __shared__ float F[ACCF_STRIDE];
  for (int e = t; e < ACCF_STRIDE; e += 256) F[e] = accF[(size_t)bh * ACCF_STRIDE + e];
  __syncthreads();
  const float* MLL = F;
  const float* MLQ = F + 256;
  const float* RRS = F + 1280;
  const float* KRT = F + 1536;
  const float* C1 = F + 2560;
  const float* C2 = F + 2576;
  const float* SRN = F + 2592;

  const int j = blockIdx.x * 256 + t;

  // ---- row part: lp update ----
  {
    size_t base = ((size_t)bh * S_ + j) * R_;
    const float4* s4 = (const float4*)(lp_src + base);
    float4 a0 = s4[0], a1 = s4[1], a2 = s4[2], a3 = s4[3];
    float lv[16] = {a0.x, a0.y, a0.z, a0.w, a1.x, a1.y, a1.z, a1.w,
                    a2.x, a2.y, a2.z, a2.w, a3.x, a3.y, a3.z, a3.w};
    float n2 = 0.f;
#pragma unroll
    for (int l = 0; l < 16; ++l) n2 += lv[l] * lv[l];
    float ri = rsqrtf(n2);
    float ls[16], L[16];
#pragma unroll
    for (int l = 0; l < 16; ++l) { ls[l] = lv[l] * ri; L[l] = ls[l] * ls[l]; }
    float dl[16];
#pragma unroll
    for (int l = 0; l < 16; ++l) dl[l] = 0.f;
    const float4* RR4 = (const float4*)RRS;
#pragma unroll
    for (int k = 0; k < 16; ++k) {
      float Lk = L[k];
#pragma unroll
      for (int g = 0; g < 4; ++g) {
        float4 rr = RR4[k * 4 + g];
        dl[4 * g + 0] += Lk * rr.x; dl[4 * g + 1] += Lk * rr.y;
        dl[4 * g + 2] += Lk * rr.z; dl[4 * g + 3] += Lk * rr.w;
      }
    }
    const float4* q4 = (const float4*)(q + ((size_t)bh * S_ + j) * D_);
    const float4* KR4 = (const float4*)KRT;
#pragma unroll
    for (int a4 = 0; a4 < 16; ++a4) {
      float4 qq = q4[a4];
#pragma unroll
      for (int c = 0; c < 4; ++c) {
        float qa = (c == 0) ? qq.x : (c == 1) ? qq.y : (c == 2) ? qq.z : qq.w;
        int a = a4 * 4 + c;
#pragma unroll
        for (int g = 0; g < 4; ++g) {
          float4 kr = KR4[a * 4 + g];
          dl[4 * g + 0] -= qa * kr.x; dl[4 * g + 1] -= qa * kr.y;
          dl[4 * g + 2] -= qa * kr.z; dl[4 * g + 3] -= qa * kr.w;
        }
      }
    }
    float dot = 0.f;
#pragma unroll
    for (int l = 0; l < 16; ++l) { dl[l] *= ls[l]; dot += ls[l] * dl[l]; }
    float4 o[4];
#pragma unroll
    for (int g = 0; g < 4; ++g) {
      float v0 = lv[4 * g + 0] - STEPSZ * (dl[4 * g + 0] - ls[4 * g + 0] * dot) * ri;
      float v1 = lv[4 * g + 1] - STEPSZ * (dl[4 * g + 1] - ls[4 * g + 1] * dot) * ri;
      float v2 = lv[4 * g + 2] - STEPSZ * (dl[4 * g + 2] - ls[4 * g + 2] * dot) * ri;
      float v3 = lv[4 * g + 3] - STEPSZ * (dl[4 * g + 3] - ls[4 * g + 3] * dot) * ri;
      o[g] = make_float4(v0, v1, v2, v3);
    }
    float4* d4 = (float4*)(lp_dst + base);
    d4[0] = o[0]; d4[1] = o[1]; d4[2] = o[2]; d4[3] = o[3];
  }

  // ---- col part: rp update (dr2 in registers, PJ folded into C1/C2) ----
  {
    const int i = j;
    size_t cbase = (size_t)bh * R_ * S_ + i;
    float rv[16], rp2[16];
#pragma unroll
    for (int l = 0; l < 16; ++l) {
      float x = rp_src[cbase + (size_t)l * S_];
      rv[l] = x;
      rp2[l] = x * x;
    }
    const float4* k4 = (const float4*)(key + ((size_t)bh * S_ + i) * D_);
    float kv[64];
#pragma unroll
    for (int a4 = 0; a4 < 16; ++a4) {
      float4 x = k4[a4];
      kv[4 * a4 + 0] = x.x; kv[4 * a4 + 1] = x.y;
      kv[4 * a4 + 2] = x.z; kv[4 * a4 + 3] = x.w;
    }
    const float4* MLL4 = (const float4*)MLL;
    const float4* MLQ4 = (const float4*)MLQ;
#pragma unroll
    for (int k = 0; k < 16; ++k) {
      float s = 0.f;
#pragma unroll
      for (int g = 0; g < 4; ++g) {
        float4 m = MLL4[k * 4 + g];
        s += m.x * rp2[4 * g + 0] + m.y * rp2[4 * g + 1] +
             m.z * rp2[4 * g + 2] + m.w * rp2[4 * g + 3];
      }
#pragma unroll
      for (int a4 = 0; a4 < 16; ++a4) {
        float4 m = MLQ4[k * 16 + a4];
        s -= m.x * kv[4 * a4 + 0] + m.y * kv[4 * a4 + 1] +
             m.z * kv[4 * a4 + 2] + m.w * kv[4 * a4 + 3];
      }
      float rs = rv[k] * SRN[k];
      float d2 = rs * s;
      rp_dst[cbase + (size_t)k * S_] = C1[k] * rv[k] - C2[k] * d2;
    }
  }
}

// ---------------------------------------------------------------------------
// kRV: partials of RV[k][d] = sum_i rp2[k][i]*v[i][d]  and final N[k].
// ---------------------------------------------------------------------------
__global__ void __launch_bounds__(256) kRV(const float* __restrict__ rp,
                                           const float* __restrict__ vv,
                                           float* __restrict__ part) {
  const int bh = blockIdx.y, bx = blockIdx.x, t = threadIdx.x;
  const int tc = t & 15, trw = t >> 4, w = t >> 6;
  __shared__ float lds[5120];   // stage 4096 / red 4*1280, time-shared
  const int j0 = bx * 256;
  {
    size_t cb = (size_t)bh * R_ * S_ + j0 + t;
    float* st = lds + t * 16;
#pragma unroll
    for (int l = 0; l < 16; ++l) {
      float x = rp[cb + (size_t)l * S_];
      st[l] = x * x;
    }
  }
  __syncthreads();
  float acc[4][16], accN[16];
#pragma unroll
  for (int u = 0; u < 4; ++u)
#pragma unroll
    for (int l = 0; l < 16; ++l) acc[u][l] = 0.f;
#pragma unroll
  for (int l = 0; l < 16; ++l) accN[l] = 0.f;
  const float* vb = vv + (size_t)bh * S_ * D_;
  for (int it = 0; it < 16; ++it) {
    int jl = trw + (it << 4);
    const float4* R4 = (const float4*)(lds + jl * 16);
    float4 b0 = R4[0], b1 = R4[1], b2 = R4[2], b3 = R4[3];
    float rv[16] = {b0.x, b0.y, b0.z, b0.w, b1.x, b1.y, b1.z, b1.w,
                    b2.x, b2.y, b2.z, b2.w, b3.x, b3.y, b3.z, b3.w};
    float kv[4];
#pragma unroll
    for (int u = 0; u < 4; ++u) kv[u] = vb[(size_t)(j0 + jl) * D_ + tc + (u << 4)];
#pragma unroll
    for (int u = 0; u < 4; ++u)
#pragma unroll
      for (int l = 0; l < 16; ++l) acc[u][l] += rv[l] * kv[u];
#pragma unroll
    for (int l = 0; l < 16; ++l) accN[l] += rv[l];
  }
#pragma unroll
  for (int u = 0; u < 4; ++u)
#pragma unroll
    for (int l = 0; l < 16; ++l) {
      float v = acc[u][l];
      v += __shfl_xor(v, 16);
      v += __shfl_xor(v, 32);
      acc[u][l] = v;
    }
#pragma unroll
  for (int l = 0; l < 16; ++l) {
    float v = accN[l];
    v += __shfl_xor(v, 16);
    v += __shfl_xor(v, 32);
    accN[l] = v;
  }
  __syncthreads();
  if ((t & 63) < 16) {
#pragma unroll
    for (int u = 0; u < 4; ++u)
#pragma unroll
      for (int l = 0; l < 16; ++l) lds[w * 1280 + tc * 80 + u * 16 + l] = acc[u][l];
    if (tc == 0) {
#pragma unroll
      for (int l = 0; l < 16; ++l) lds[w * 1280 + 64 + l] = accN[l];
    }
  }
  __syncthreads();
  float* pb = part + (size_t)(bh * 32 + bx) * PART2_STRIDE;
#pragma unroll
  for (int r = 0; r < 4; ++r) {
    int o = t + r * 256;
    int sl = o >> 4, c = o & 15;
    pb[o] = lds[c * 80 + sl] + lds[1280 + c * 80 + sl] +
            lds[2560 + c * 80 + sl] + lds[3840 + c * 80 + sl];
  }
  if (t < 16)
    pb[1024 + t] = lds[64 + t] + lds[1280 + 64 + t] + lds[2560 + 64 + t] + lds[3840 + 64 + t];
}

__global__ void __launch_bounds__(256) kBF(const float* __restrict__ part,
                                           float* __restrict__ RVs) {
  const int bh = blockIdx.x, t = threadIdx.x;
  __shared__ float raw[PART2_STRIDE];
  __shared__ float inn[16];
  const float* p0 = part + (size_t)bh * 32 * PART2_STRIDE;
  for (int v = t; v < PART2_STRIDE; v += 256) {
    float s = 0.f;
    const float* p = p0 + v;
#pragma unroll 8
    for (int b = 0; b < 32; ++b) s += p[(size_t)b * PART2_STRIDE];
    raw[v] = s;
  }
  __syncthreads();
  if (t < 16) inn[t] = 1.0f / raw[1024 + t];
  __syncthreads();
#pragma unroll
  for (int r = 0; r < 4; ++r) {
    int e = t + r * 256;
    int k = e >> 6, d = e & 63, u = d >> 4, c = d & 15;
    RVs[(size_t)bh * 1024 + e] = raw[(u * 16 + k) * 16 + c] * inn[k];
  }
}

// out[j][d] = sum_k unit(lp_j)^2[k] * RVs[k][d]   (RVs pre-scaled)
__global__ void __launch_bounds__(256) kOut(const float* __restrict__ lp,
                                            const float* __restrict__ RVs,
                                            float* __restrict__ out) {
  const int bh = blockIdx.y, t = threadIdx.x;
  __shared__ float rvs[1024];
#pragma unroll
  for (int r = 0; r < 4; ++r) rvs[t + r * 256] = RVs[(size_t)bh * 1024 + t + r * 256];
  __syncthreads();
  const int j = blockIdx.x * 256 + t;
  size_t base = ((size_t)bh * S_ + j) * R_;
  const float4* lp4 = (const float4*)(lp + base);
  float4 a0 = lp4[0], a1 = lp4[1], a2 = lp4[2], a3 = lp4[3];
  float lv[16] = {a0.x, a0.y, a0.z, a0.w, a1.x, a1.y, a1.z, a1.w,
                  a2.x, a2.y, a2.z, a2.w, a3.x, a3.y, a3.z, a3.w};
  float n2 = 0.f;
#pragma unroll
  for (int l = 0; l < 16; ++l) n2 += lv[l] * lv[l];
  float r2 = 1.0f / n2;
  float L[16];
#pragma unroll
  for (int l = 0; l < 16; ++l) L[l] = lv[l] * lv[l] * r2;
  float o[64];
#pragma unroll
  for (int d = 0; d < 64; ++d) o[d] = 0.f;
  const float4* rv4 = (const float4*)rvs;
#pragma unroll
  for (int k = 0; k < 16; ++k) {
    float Lk = L[k];
#pragma unroll
    for (int d4 = 0; d4 < 16; ++d4) {
      float4 r = rv4[k * 16 + d4];
      o[4 * d4 + 0] += Lk * r.x; o[4 * d4 + 1] += Lk * r.y;
      o[4 * d4 + 2] += Lk * r.z; o[4 * d4 + 3] += Lk * r.w;
    }
  }
  float4* o4 = (float4*)(out + ((size_t)bh * S_ + j) * D_);
#pragma unroll
  for (int d4 = 0; d4 < 16; ++d4)
    o4[d4] = make_float4(o[4 * d4 + 0], o[4 * d4 + 1], o[4 * d4 + 2], o[4 * d4 + 3]);
}

extern "C" void kernel_launch(void* const* d_in, const int* in_sizes, int n_in,
                              void* d_out, int out_size, void* d_ws, size_t ws_size,
                              hipStream_t stream) {
  (void)in_sizes; (void)n_in; (void)out_size; (void)ws_size;
  const float* q = (const float*)d_in[0];
  const float* key = (const float*)d_in[1];
  const float* v = (const float*)d_in[2];
  const float* lp0 = (const float*)d_in[3];
  const float* rp0 = (const float*)d_in[4];
  float* out = (float*)d_out;
  float* ws = (float*)d_ws;

  float* lp = ws;                    // 3,145,728
  float* rp = lp + LP_N;             // 3,145,728
  float* part = rp + LP_N;           // 1,978,368  (reused by kRV: 24*32*1040 fits)
  float* accF = part + PART_N;       // 62,976
  float* RVs = accF + ACCF_N;        // 24,576
  // total 8,357,376 floats = 33.4 MB

  dim3 blk(256);
  dim3 gA(32, BH_);
  for (int s = 0; s < 10; ++s) {
    const float* lsrc = (s == 0) ? lp0 : lp;
    const float* rsrc = (s == 0) ? rp0 : rp;
    kA<<<gA, blk, 0, stream>>>(lsrc, rsrc, q, key, part);
    kB<<<dim3(BH_), blk, 0, stream>>>(part, accF);
    kC<<<gA, blk, 0, stream>>>(accF, q, key, lsrc, rsrc, lp, rp);
  }
  kRV<<<gA, blk, 0, stream>>>(rp, v, part);
  kBF<<<dim3(BH_), blk, 0, stream>>>(part, RVs);
  kOut<<<gA, blk, 0, stream>>>(lp, RVs, out);
}

// Round 3
// 957.410 us; speedup vs baseline: 2.8907x; 1.2726x over previous
//
#include <hip/hip_runtime.h>

// LowRankAttention: B=2,H=12 (BH=24), S=8192, D=64, RANK=16, 10 steps, fp32.
#define S_ 8192
#define D_ 64
#define R_ 16
#define BH_ 24

static constexpr float INV_S2 = 1.0f / (8192.0f * 8192.0f);
static constexpr float STEPSZ = 1000.0f;
static constexpr float CC = 2.0f * INV_S2;

#define LP_N (BH_ * S_ * R_)          // 3,145,728 floats
#define PART_STRIDE 2576              // L:0..1279, R:1280..2559, N:2560..2575
#define PART_N (BH_ * 32 * PART_STRIDE)
#define ACCF_STRIDE 2624              // MLL 0, MLQ 256, RRS 1280, KRT 1536, C1 2560, C2 2576, SRN 2592, INN 2608
#define ACCF_N (BH_ * ACCF_STRIDE)
#define PART2_STRIDE 1040             // RV:0..1023, N:1024..1039
#define PART2_N (BH_ * 32 * PART2_STRIDE)

// ---------------------------------------------------------------------------
// kA: initial partial reductions from (lp0, rp0).  Block (bx,bh): 256 rows+cols.
// ---------------------------------------------------------------------------
__global__ void __launch_bounds__(256) kA(const float* __restrict__ lp_src,
                                          const float* __restrict__ rp_src,
                                          const float* __restrict__ q,
                                          const float* __restrict__ key,
                                          float* __restrict__ part) {
  const int bh = blockIdx.y, bx = blockIdx.x, t = threadIdx.x;
  const int tc = t & 15, trw = t >> 4, w = t >> 6;
  __shared__ float lds[6144];
  const int j0 = bx * 256;

  {
    size_t base = ((size_t)bh * S_ + j0 + t) * R_;
    const float4* s4 = (const float4*)(lp_src + base);
    float4 a0 = s4[0], a1 = s4[1], a2 = s4[2], a3 = s4[3];
    float n2 = a0.x*a0.x + a0.y*a0.y + a0.z*a0.z + a0.w*a0.w
             + a1.x*a1.x + a1.y*a1.y + a1.z*a1.z + a1.w*a1.w
             + a2.x*a2.x + a2.y*a2.y + a2.z*a2.z + a2.w*a2.w
             + a3.x*a3.x + a3.y*a3.y + a3.z*a3.z + a3.w*a3.w;
    float r2 = 1.0f / n2;
    float4* st = (float4*)(lds + t * 16);
    st[0] = make_float4(a0.x*a0.x*r2, a0.y*a0.y*r2, a0.z*a0.z*r2, a0.w*a0.w*r2);
    st[1] = make_float4(a1.x*a1.x*r2, a1.y*a1.y*r2, a1.z*a1.z*r2, a1.w*a1.w*r2);
    st[2] = make_float4(a2.x*a2.x*r2, a2.y*a2.y*r2, a2.z*a2.z*r2, a2.w*a2.w*r2);
    st[3] = make_float4(a3.x*a3.x*r2, a3.y*a3.y*r2, a3.z*a3.z*r2, a3.w*a3.w*r2);
  }
  __syncthreads();

  float acc[5][16];
#pragma unroll
  for (int u = 0; u < 5; ++u)
#pragma unroll
    for (int l = 0; l < 16; ++l) acc[u][l] = 0.f;

  const float* qb = q + (size_t)bh * S_ * D_;
  for (int it = 0; it < 16; ++it) {
    int jl = trw + (it << 4);
    const float4* L4 = (const float4*)(lds + jl * 16);
    float4 b0 = L4[0], b1 = L4[1], b2 = L4[2], b3 = L4[3];
    float Lv[16] = {b0.x, b0.y, b0.z, b0.w, b1.x, b1.y, b1.z, b1.w,
                    b2.x, b2.y, b2.z, b2.w, b3.x, b3.y, b3.z, b3.w};
    float Lc = lds[jl * 16 + tc];
    float qv[4];
#pragma unroll
    for (int u = 0; u < 4; ++u) qv[u] = qb[(size_t)(j0 + jl) * D_ + tc + (u << 4)];
#pragma unroll
    for (int u = 0; u < 4; ++u)
#pragma unroll
      for (int l = 0; l < 16; ++l) acc[u][l] += Lv[l] * qv[u];
#pragma unroll
    for (int l = 0; l < 16; ++l) acc[4][l] += Lv[l] * Lc;
  }
#pragma unroll
  for (int u = 0; u < 5; ++u)
#pragma unroll
    for (int l = 0; l < 16; ++l) {
      float v = acc[u][l];
      v += __shfl_xor(v, 16);
      v += __shfl_xor(v, 32);
      acc[u][l] = v;
    }
  __syncthreads();
  if ((t & 63) < 16) {
#pragma unroll
    for (int u = 0; u < 5; ++u)
#pragma unroll
      for (int l = 0; l < 16; ++l) lds[w * 1536 + tc * 96 + u * 16 + l] = acc[u][l];
  }
  __syncthreads();
  float* pb = part + (size_t)(bh * 32 + bx) * PART_STRIDE;
#pragma unroll
  for (int r = 0; r < 5; ++r) {
    int o = t + r * 256;
    int sl = o >> 4, c = o & 15;
    pb[o] = lds[c * 96 + sl] + lds[1536 + c * 96 + sl] +
            lds[3072 + c * 96 + sl] + lds[4608 + c * 96 + sl];
  }
  __syncthreads();

  {
    size_t cb = (size_t)bh * R_ * S_ + j0 + t;
    float* st = lds + t * 16;
#pragma unroll
    for (int l = 0; l < 16; ++l) {
      float x = rp_src[cb + (size_t)l * S_];
      st[l] = x * x;
    }
  }
  __syncthreads();

  float accN[16];
#pragma unroll
  for (int u = 0; u < 5; ++u)
#pragma unroll
    for (int l = 0; l < 16; ++l) acc[u][l] = 0.f;
#pragma unroll
  for (int l = 0; l < 16; ++l) accN[l] = 0.f;

  const float* kb = key + (size_t)bh * S_ * D_;
  for (int it = 0; it < 16; ++it) {
    int jl = trw + (it << 4);
    const float4* R4 = (const float4*)(lds + jl * 16);
    float4 b0 = R4[0], b1 = R4[1], b2 = R4[2], b3 = R4[3];
    float rv[16] = {b0.x, b0.y, b0.z, b0.w, b1.x, b1.y, b1.z, b1.w,
                    b2.x, b2.y, b2.z, b2.w, b3.x, b3.y, b3.z, b3.w};
    float rc = lds[jl * 16 + tc];
    float kv[4];
#pragma unroll
    for (int u = 0; u < 4; ++u) kv[u] = kb[(size_t)(j0 + jl) * D_ + tc + (u << 4)];
#pragma unroll
    for (int u = 0; u < 4; ++u)
#pragma unroll
      for (int l = 0; l < 16; ++l) acc[u][l] += rv[l] * kv[u];
#pragma unroll
    for (int l = 0; l < 16; ++l) acc[4][l] += rv[l] * rc;
#pragma unroll
    for (int l = 0; l < 16; ++l) accN[l] += rv[l];
  }
#pragma unroll
  for (int u = 0; u < 5; ++u)
#pragma unroll
    for (int l = 0; l < 16; ++l) {
      float v = acc[u][l];
      v += __shfl_xor(v, 16);
      v += __shfl_xor(v, 32);
      acc[u][l] = v;
    }
#pragma unroll
  for (int l = 0; l < 16; ++l) {
    float v = accN[l];
    v += __shfl_xor(v, 16);
    v += __shfl_xor(v, 32);
    accN[l] = v;
  }
  __syncthreads();
  if ((t & 63) < 16) {
#pragma unroll
    for (int u = 0; u < 5; ++u)
#pragma unroll
      for (int l = 0; l < 16; ++l) lds[w * 1536 + tc * 96 + u * 16 + l] = acc[u][l];
    if (tc == 0) {
#pragma unroll
      for (int l = 0; l < 16; ++l) lds[w * 1536 + 80 + l] = accN[l];
    }
  }
  __syncthreads();
#pragma unroll
  for (int r = 0; r < 5; ++r) {
    int o = t + r * 256;
    int sl = o >> 4, c = o & 15;
    pb[1280 + o] = lds[c * 96 + sl] + lds[1536 + c * 96 + sl] +
                   lds[3072 + c * 96 + sl] + lds[4608 + c * 96 + sl];
  }
  if (t < 16)
    pb[2560 + t] = lds[80 + t] + lds[1536 + 80 + t] + lds[3072 + 80 + t] + lds[4608 + 80 + t];
}

// ---------------------------------------------------------------------------
// kB: one block per bh. Sum 32 partials -> derived matrices + analytic PJ, c1/c2.
// ---------------------------------------------------------------------------
__global__ void __launch_bounds__(256) kB(const float* __restrict__ part,
                                          float* __restrict__ accF) {
  const int bh = blockIdx.x, t = threadIdx.x;
  __shared__ float raw[PART_STRIDE];
  __shared__ float inn[16], srn[16];
  const float* p0 = part + (size_t)bh * 32 * PART_STRIDE;
  for (int v = t; v < PART_STRIDE; v += 256) {
    float s = 0.f;
    const float* p = p0 + v;
#pragma unroll 8
    for (int b = 0; b < 32; ++b) s += p[(size_t)b * PART_STRIDE];
    raw[v] = s;
  }
  __syncthreads();
  if (t < 16) {
    float N = raw[2560 + t];
    inn[t] = 1.0f / N;
    srn[t] = rsqrtf(N);
  }
  __syncthreads();
  float* out = accF + (size_t)bh * ACCF_STRIDE;
  {
    int k = t >> 4, l = t & 15;
    float LLr = raw[(64 + k) * 16 + l];
    out[k * 16 + l] = LLr * CC * inn[l];                      // MLL[k][l]
    float RRr = raw[1280 + (64 + k) * 16 + l];
    out[1280 + k * 16 + l] = RRr * CC * inn[k] * inn[l];      // RRS[k][l]
  }
#pragma unroll
  for (int r = 0; r < 4; ++r) {  // MLQ[k*64+a]
    int e = t + r * 256;
    int k = e >> 6, a = e & 63, u = a >> 4, c = a & 15;
    out[256 + e] = raw[(u * 16 + k) * 16 + c] * CC;
  }
#pragma unroll
  for (int r = 0; r < 4; ++r) {  // KRT[a*16+l]
    int e = t + r * 256;
    int a = e >> 4, l = e & 15, u = a >> 4, c = a & 15;
    out[1536 + e] = raw[1280 + (u * 16 + l) * 16 + c] * CC * inn[l];
  }
  if (t < 16) {
    int k = t;
    float s = 0.f;
#pragma unroll
    for (int l = 0; l < 16; ++l)
      s += raw[(64 + k) * 16 + l] * CC * inn[l] * raw[1280 + (64 + k) * 16 + l];
#pragma unroll
    for (int a = 0; a < 64; ++a) {
      int u = a >> 4, c = a & 15;
      s -= raw[(u * 16 + k) * 16 + c] * CC * raw[1280 + (u * 16 + k) * 16 + c];
    }
    float PJ = inn[k] * s;
    out[2560 + t] = 1.0f + STEPSZ * PJ * inn[t];   // c1
    out[2576 + t] = STEPSZ * srn[t];               // c2
    out[2592 + t] = srn[t];
    out[2608 + t] = inn[t];
  }
}

// ---------------------------------------------------------------------------
// kStep: fused update + next-step partial reduction.
//   z=0 row blocks: lp update (uses RRS,KRT), then reduce new LL/LQ partials.
//   z=1 col blocks: rp update (uses MLL,MLQ,C1,C2,SRN), then reduce new
//                   RR/KR/N partials (or RV/N from v when LAST).
// ---------------------------------------------------------------------------
template <int LAST>
__global__ void __launch_bounds__(256) kStep(const float* __restrict__ accF,
                                             const float* __restrict__ q,
                                             const float* __restrict__ key,
                                             const float* __restrict__ vv,
                                             const float* __restrict__ lp_src,
                                             const float* __restrict__ rp_src,
                                             float* __restrict__ lp_dst,
                                             float* __restrict__ rp_dst,
                                             float* __restrict__ part,
                                             float* __restrict__ part2) {
  const int bh = blockIdx.y, bx = blockIdx.x, t = threadIdx.x;
  const int tc = t & 15, trw = t >> 4, w = t >> 6;
  const int j0 = bx * 256;
  __shared__ float F[1344];
  __shared__ float lds[6144];
  const float* A = accF + (size_t)bh * ACCF_STRIDE;

  if (blockIdx.z == 0) {
    // ================= row side =================
    for (int e = t; e < 1280; e += 256) F[e] = A[1280 + e];  // RRS(256)+KRT(1024)
    __syncthreads();
    const float4* RR4 = (const float4*)F;
    const float4* KR4 = (const float4*)(F + 256);

    size_t base = ((size_t)bh * S_ + j0 + t) * R_;
    const float4* s4 = (const float4*)(lp_src + base);
    float4 a0 = s4[0], a1 = s4[1], a2 = s4[2], a3 = s4[3];
    float lv[16] = {a0.x, a0.y, a0.z, a0.w, a1.x, a1.y, a1.z, a1.w,
                    a2.x, a2.y, a2.z, a2.w, a3.x, a3.y, a3.z, a3.w};
    float n2 = 0.f;
#pragma unroll
    for (int l = 0; l < 16; ++l) n2 += lv[l] * lv[l];
    float ri = rsqrtf(n2);
    float ls[16], L[16];
#pragma unroll
    for (int l = 0; l < 16; ++l) { ls[l] = lv[l] * ri; L[l] = ls[l] * ls[l]; }
    float dl[16];
#pragma unroll
    for (int l = 0; l < 16; ++l) dl[l] = 0.f;
#pragma unroll
    for (int k = 0; k < 16; ++k) {
      float Lk = L[k];
#pragma unroll
      for (int g = 0; g < 4; ++g) {
        float4 rr = RR4[k * 4 + g];
        dl[4 * g + 0] += Lk * rr.x; dl[4 * g + 1] += Lk * rr.y;
        dl[4 * g + 2] += Lk * rr.z; dl[4 * g + 3] += Lk * rr.w;
      }
    }
    const float4* q4 = (const float4*)(q + ((size_t)bh * S_ + j0 + t) * D_);
#pragma unroll
    for (int a4 = 0; a4 < 16; ++a4) {
      float4 qq = q4[a4];
#pragma unroll
      for (int c = 0; c < 4; ++c) {
        float qa = (c == 0) ? qq.x : (c == 1) ? qq.y : (c == 2) ? qq.z : qq.w;
        int a = a4 * 4 + c;
#pragma unroll
        for (int g = 0; g < 4; ++g) {
          float4 kr = KR4[a * 4 + g];
          dl[4 * g + 0] -= qa * kr.x; dl[4 * g + 1] -= qa * kr.y;
          dl[4 * g + 2] -= qa * kr.z; dl[4 * g + 3] -= qa * kr.w;
        }
      }
    }
    float dot = 0.f;
#pragma unroll
    for (int l = 0; l < 16; ++l) { dl[l] *= ls[l]; dot += ls[l] * dl[l]; }
#pragma unroll
    for (int l = 0; l < 16; ++l)
      lv[l] -= STEPSZ * (dl[l] - ls[l] * dot) * ri;
    float4* d4 = (float4*)(lp_dst + base);
    d4[0] = make_float4(lv[0], lv[1], lv[2], lv[3]);
    d4[1] = make_float4(lv[4], lv[5], lv[6], lv[7]);
    d4[2] = make_float4(lv[8], lv[9], lv[10], lv[11]);
    d4[3] = make_float4(lv[12], lv[13], lv[14], lv[15]);

    if (LAST) return;   // block-uniform

    // stage L_new, reduce LL/LQ
    float m2 = 0.f;
#pragma unroll
    for (int l = 0; l < 16; ++l) m2 += lv[l] * lv[l];
    float r2 = 1.0f / m2;
    {
      float4* st = (float4*)(lds + t * 16);
      st[0] = make_float4(lv[0]*lv[0]*r2, lv[1]*lv[1]*r2, lv[2]*lv[2]*r2, lv[3]*lv[3]*r2);
      st[1] = make_float4(lv[4]*lv[4]*r2, lv[5]*lv[5]*r2, lv[6]*lv[6]*r2, lv[7]*lv[7]*r2);
      st[2] = make_float4(lv[8]*lv[8]*r2, lv[9]*lv[9]*r2, lv[10]*lv[10]*r2, lv[11]*lv[11]*r2);
      st[3] = make_float4(lv[12]*lv[12]*r2, lv[13]*lv[13]*r2, lv[14]*lv[14]*r2, lv[15]*lv[15]*r2);
    }
    __syncthreads();
    float acc[5][16];
#pragma unroll
    for (int u = 0; u < 5; ++u)
#pragma unroll
      for (int l = 0; l < 16; ++l) acc[u][l] = 0.f;
    const float* qb = q + (size_t)bh * S_ * D_;
    for (int it = 0; it < 16; ++it) {
      int jl = trw + (it << 4);
      const float4* L4 = (const float4*)(lds + jl * 16);
      float4 b0 = L4[0], b1 = L4[1], b2 = L4[2], b3 = L4[3];
      float Lv[16] = {b0.x, b0.y, b0.z, b0.w, b1.x, b1.y, b1.z, b1.w,
                      b2.x, b2.y, b2.z, b2.w, b3.x, b3.y, b3.z, b3.w};
      float Lc = lds[jl * 16 + tc];
      float qv[4];
#pragma unroll
      for (int u = 0; u < 4; ++u) qv[u] = qb[(size_t)(j0 + jl) * D_ + tc + (u << 4)];
#pragma unroll
      for (int u = 0; u < 4; ++u)
#pragma unroll
        for (int l = 0; l < 16; ++l) acc[u][l] += Lv[l] * qv[u];
#pragma unroll
      for (int l = 0; l < 16; ++l) acc[4][l] += Lv[l] * Lc;
    }
#pragma unroll
    for (int u = 0; u < 5; ++u)
#pragma unroll
      for (int l = 0; l < 16; ++l) {
        float v = acc[u][l];
        v += __shfl_xor(v, 16);
        v += __shfl_xor(v, 32);
        acc[u][l] = v;
      }
    __syncthreads();
    if ((t & 63) < 16) {
#pragma unroll
      for (int u = 0; u < 5; ++u)
#pragma unroll
        for (int l = 0; l < 16; ++l) lds[w * 1536 + tc * 96 + u * 16 + l] = acc[u][l];
    }
    __syncthreads();
    float* pb = part + (size_t)(bh * 32 + bx) * PART_STRIDE;
#pragma unroll
    for (int r = 0; r < 5; ++r) {
      int o = t + r * 256;
      int sl = o >> 4, c = o & 15;
      pb[o] = lds[c * 96 + sl] + lds[1536 + c * 96 + sl] +
              lds[3072 + c * 96 + sl] + lds[4608 + c * 96 + sl];
    }
  } else {
    // ================= col side =================
    for (int e = t; e < 1328; e += 256) F[e] = (e < 1280) ? A[e] : A[1280 + e];
    __syncthreads();
    const float4* MLL4 = (const float4*)F;
    const float4* MLQ4 = (const float4*)(F + 256);
    const float* C1 = F + 1280;
    const float* C2 = F + 1296;
    const float* SRN = F + 1312;

    const int i = j0 + t;
    size_t cbase = (size_t)bh * R_ * S_ + i;
    float rv[16], rp2[16];
#pragma unroll
    for (int l = 0; l < 16; ++l) {
      float x = rp_src[cbase + (size_t)l * S_];
      rv[l] = x;
      rp2[l] = x * x;
    }
    float s[16];
#pragma unroll
    for (int k = 0; k < 16; ++k) {
      float acc0 = 0.f;
#pragma unroll
      for (int g = 0; g < 4; ++g) {
        float4 m = MLL4[k * 4 + g];
        acc0 += m.x * rp2[4 * g + 0] + m.y * rp2[4 * g + 1] +
                m.z * rp2[4 * g + 2] + m.w * rp2[4 * g + 3];
      }
      s[k] = acc0;
    }
    const float4* k4 = (const float4*)(key + ((size_t)bh * S_ + i) * D_);
#pragma unroll
    for (int a4 = 0; a4 < 16; ++a4) {
      float4 kk = k4[a4];
#pragma unroll
      for (int k = 0; k < 16; ++k) {
        float4 m = MLQ4[k * 16 + a4];
        s[k] -= m.x * kk.x + m.y * kk.y + m.z * kk.z + m.w * kk.w;
      }
    }
#pragma unroll
    for (int k = 0; k < 16; ++k) {
      float rs = rv[k] * SRN[k];
      float d2 = rs * s[k];
      float nv = C1[k] * rv[k] - C2[k] * d2;
      rp_dst[cbase + (size_t)k * S_] = nv;
      rp2[k] = nv * nv;
    }
    {
      float* st = lds + t * 16;
#pragma unroll
      for (int l = 0; l < 16; ++l) st[l] = rp2[l];
    }
    __syncthreads();
    float acc[5][16], accN[16];
#pragma unroll
    for (int u = 0; u < 5; ++u)
#pragma unroll
      for (int l = 0; l < 16; ++l) acc[u][l] = 0.f;
#pragma unroll
    for (int l = 0; l < 16; ++l) accN[l] = 0.f;
    const float* sb = (LAST ? vv : key) + (size_t)bh * S_ * D_;
    for (int it = 0; it < 16; ++it) {
      int jl = trw + (it << 4);
      const float4* R4 = (const float4*)(lds + jl * 16);
      float4 b0 = R4[0], b1 = R4[1], b2 = R4[2], b3 = R4[3];
      float rw[16] = {b0.x, b0.y, b0.z, b0.w, b1.x, b1.y, b1.z, b1.w,
                      b2.x, b2.y, b2.z, b2.w, b3.x, b3.y, b3.z, b3.w};
      float rc = lds[jl * 16 + tc];
      float kv[4];
#pragma unroll
      for (int u = 0; u < 4; ++u) kv[u] = sb[(size_t)(j0 + jl) * D_ + tc + (u << 4)];
#pragma unroll
      for (int u = 0; u < 4; ++u)
#pragma unroll
        for (int l = 0; l < 16; ++l) acc[u][l] += rw[l] * kv[u];
#pragma unroll
      for (int l = 0; l < 16; ++l) acc[4][l] += rw[l] * rc;
#pragma unroll
      for (int l = 0; l < 16; ++l) accN[l] += rw[l];
    }
#pragma unroll
    for (int u = 0; u < 5; ++u)
#pragma unroll
      for (int l = 0; l < 16; ++l) {
        float v = acc[u][l];
        v += __shfl_xor(v, 16);
        v += __shfl_xor(v, 32);
        acc[u][l] = v;
      }
#pragma unroll
    for (int l = 0; l < 16; ++l) {
      float v = accN[l];
      v += __shfl_xor(v, 16);
      v += __shfl_xor(v, 32);
      accN[l] = v;
    }
    __syncthreads();
    if ((t & 63) < 16) {
#pragma unroll
      for (int u = 0; u < 5; ++u)
#pragma unroll
        for (int l = 0; l < 16; ++l) lds[w * 1536 + tc * 96 + u * 16 + l] = acc[u][l];
      if (tc == 0) {
#pragma unroll
        for (int l = 0; l < 16; ++l) lds[w * 1536 + 80 + l] = accN[l];
      }
    }
    __syncthreads();
    if (!LAST) {
      float* pb = part + (size_t)(bh * 32 + bx) * PART_STRIDE;
#pragma unroll
      for (int r = 0; r < 5; ++r) {
        int o = t + r * 256;
        int sl = o >> 4, c = o & 15;
        pb[1280 + o] = lds[c * 96 + sl] + lds[1536 + c * 96 + sl] +
                       lds[3072 + c * 96 + sl] + lds[4608 + c * 96 + sl];
      }
      if (t < 16)
        pb[2560 + t] = lds[80 + t] + lds[1536 + 80 + t] + lds[3072 + 80 + t] + lds[4608 + 80 + t];
    } else {
      float* pb2 = part2 + (size_t)(bh * 32 + bx) * PART2_STRIDE;
#pragma unroll
      for (int r = 0; r < 4; ++r) {
        int o = t + r * 256;
        int sl = o >> 4, c = o & 15;
        pb2[o] = lds[c * 96 + sl] + lds[1536 + c * 96 + sl] +
                 lds[3072 + c * 96 + sl] + lds[4608 + c * 96 + sl];
      }
      if (t < 16)
        pb2[1024 + t] = lds[80 + t] + lds[1536 + 80 + t] + lds[3072 + 80 + t] + lds[4608 + 80 + t];
    }
  }
}

// ---------------------------------------------------------------------------
// kBF: sum RV partials, scale by 1/N -> RVs[k][d]
// ---------------------------------------------------------------------------
__global__ void __launch_bounds__(256) kBF(const float* __restrict__ part2,
                                           float* __restrict__ RVs) {
  const int bh = blockIdx.x, t = threadIdx.x;
  __shared__ float raw[PART2_STRIDE];
  __shared__ float inn[16];
  const float* p0 = part2 + (size_t)bh * 32 * PART2_STRIDE;
  for (int v = t; v < PART2_STRIDE; v += 256) {
    float s = 0.f;
    const float* p = p0 + v;
#pragma unroll 8
    for (int b = 0; b < 32; ++b) s += p[(size_t)b * PART2_STRIDE];
    raw[v] = s;
  }
  __syncthreads();
  if (t < 16) inn[t] = 1.0f / raw[1024 + t];
  __syncthreads();
#pragma unroll
  for (int r = 0; r < 4; ++r) {
    int e = t + r * 256;
    int k = e >> 6, d = e & 63, u = d >> 4, c = d & 15;
    RVs[(size_t)bh * 1024 + e] = raw[(u * 16 + k) * 16 + c] * inn[k];
  }
}

// out[j][d] = sum_k unit(lp_j)^2[k] * RVs[k][d]
__global__ void __launch_bounds__(256) kOut(const float* __restrict__ lp,
                                            const float* __restrict__ RVs,
                                            float* __restrict__ out) {
  const int bh = blockIdx.y, t = threadIdx.x;
  __shared__ float rvs[1024];
#pragma unroll
  for (int r = 0; r < 4; ++r) rvs[t + r * 256] = RVs[(size_t)bh * 1024 + t + r * 256];
  __syncthreads();
  const int j = blockIdx.x * 256 + t;
  size_t base = ((size_t)bh * S_ + j) * R_;
  const float4* lp4 = (const float4*)(lp + base);
  float4 a0 = lp4[0], a1 = lp4[1], a2 = lp4[2], a3 = lp4[3];
  float lv[16] = {a0.x, a0.y, a0.z, a0.w, a1.x, a1.y, a1.z, a1.w,
                  a2.x, a2.y, a2.z, a2.w, a3.x, a3.y, a3.z, a3.w};
  float n2 = 0.f;
#pragma unroll
  for (int l = 0; l < 16; ++l) n2 += lv[l] * lv[l];
  float r2 = 1.0f / n2;
  float L[16];
#pragma unroll
  for (int l = 0; l < 16; ++l) L[l] = lv[l] * lv[l] * r2;
  float o[64];
#pragma unroll
  for (int d = 0; d < 64; ++d) o[d] = 0.f;
  const float4* rv4 = (const float4*)rvs;
#pragma unroll
  for (int k = 0; k < 16; ++k) {
    float Lk = L[k];
#pragma unroll
    for (int d4 = 0; d4 < 16; ++d4) {
      float4 r = rv4[k * 16 + d4];
      o[4 * d4 + 0] += Lk * r.x; o[4 * d4 + 1] += Lk * r.y;
      o[4 * d4 + 2] += Lk * r.z; o[4 * d4 + 3] += Lk * r.w;
    }
  }
  float4* o4 = (float4*)(out + ((size_t)bh * S_ + j) * D_);
#pragma unroll
  for (int d4 = 0; d4 < 16; ++d4)
    o4[d4] = make_float4(o[4 * d4 + 0], o[4 * d4 + 1], o[4 * d4 + 2], o[4 * d4 + 3]);
}

extern "C" void kernel_launch(void* const* d_in, const int* in_sizes, int n_in,
                              void* d_out, int out_size, void* d_ws, size_t ws_size,
                              hipStream_t stream) {
  (void)in_sizes; (void)n_in; (void)out_size; (void)ws_size;
  const float* q = (const float*)d_in[0];
  const float* key = (const float*)d_in[1];
  const float* v = (const float*)d_in[2];
  const float* lp0 = (const float*)d_in[3];
  const float* rp0 = (const float*)d_in[4];
  float* out = (float*)d_out;
  float* ws = (float*)d_ws;

  float* lp = ws;                    // 3,145,728
  float* rp = lp + LP_N;             // 3,145,728
  float* part = rp + LP_N;           // 1,978,368
  float* accF = part + PART_N;       // 62,976
  float* part2 = accF + ACCF_N;      // 798,720
  float* RVs = part2 + PART2_N;      // 24,576
  // total ~9.16M floats = 36.6 MB

  dim3 blk(256);
  dim3 gA(32, BH_);
  dim3 gS(32, BH_, 2);
  kA<<<gA, blk, 0, stream>>>(lp0, rp0, q, key, part);
  for (int s = 0; s < 10; ++s) {
    kB<<<dim3(BH_), blk, 0, stream>>>(part, accF);
    const float* lsrc = (s == 0) ? lp0 : lp;
    const float* rsrc = (s == 0) ? rp0 : rp;
    if (s < 9)
      kStep<0><<<gS, blk, 0, stream>>>(accF, q, key, v, lsrc, rsrc, lp, rp, part, part2);
    else
      kStep<1><<<gS, blk, 0, stream>>>(accF, q, key, v, lsrc, rsrc, lp, rp, part, part2);
  }
  kBF<<<dim3(BH_), blk, 0, stream>>>(part2, RVs);
  kOut<<<gA, blk, 0, stream>>>(lp, RVs, out);
}

// Round 4
// 933.012 us; speedup vs baseline: 2.9663x; 1.0261x over previous
//
#include <hip/hip_runtime.h>

// LowRankAttention: B=2,H=12 (BH=24), S=8192, D=64, RANK=16, 10 steps, fp32.
#define S_ 8192
#define D_ 64
#define R_ 16
#define BH_ 24

static constexpr float INV_S2 = 1.0f / (8192.0f * 8192.0f);
static constexpr float STEPSZ = 1000.0f;
static constexpr float CC = 2.0f * INV_S2;

#define LP_N (BH_ * S_ * R_)
// part layout per (bh,block): L-side 1280 (LQ: a*16+l for a=0..63; LL: 1024+l*16+c),
//                             R-side at 1280 (KR: a*16+l; RR: 1024+k*16+l), N at 2560.
#define PART_STRIDE 2576
#define PART_N (BH_ * 32 * PART_STRIDE)
#define ACCF_STRIDE 2624  // MLL 0, MLQ 256, RRS 1280, KRT 1536, C1 2560, C2 2576, SRN 2592, INN 2608
#define ACCF_N (BH_ * ACCF_STRIDE)
#define PART2_STRIDE 1040  // RV: d*16+l (d=0..63); N at 1024
#define PART2_N (BH_ * 32 * PART2_STRIDE)

// ---------------------------------------------------------------------------
// kStep<MODE>: MODE 0 = init (copy lp0/rp0 in, reduce only)
//              MODE 1 = mid  (update + reduce for next step)
//              MODE 2 = last (update; col side reduces RV/N from v)
// z=0: row side (lp, q).  z=1: col side (rp transposed [i][16], key/v).
// Shared buffer B[6400] time-shares: F (<=1328) -> stage (4096) -> red (4*1600).
// ---------------------------------------------------------------------------
template <int MODE>
__global__ void __launch_bounds__(256) kStep(const float* __restrict__ accF,
                                             const float* __restrict__ q,
                                             const float* __restrict__ key,
                                             const float* __restrict__ vv,
                                             const float* __restrict__ lp_src,
                                             const float* __restrict__ rp_src,
                                             float* __restrict__ lp_dst,
                                             float* __restrict__ rp_dst,
                                             float* __restrict__ part,
                                             float* __restrict__ part2) {
  const int bh = blockIdx.y, bx = blockIdx.x, t = threadIdx.x;
  const int tc = t & 15, trw = t >> 4, w = t >> 6, lane = t & 63;
  const int j0 = bx * 256;
  __shared__ float B[6400];
  const float* A = accF + (size_t)bh * ACCF_STRIDE;

  if (blockIdx.z == 0) {
    // ========================= row side =========================
    const size_t base = ((size_t)bh * S_ + j0 + t) * R_;
    float lv[16];
    if (MODE >= 1) {
      for (int e = t; e < 1280; e += 256) B[e] = A[1280 + e];  // RRS 256 + KRT 1024
      __syncthreads();
      const float4* RR4 = (const float4*)B;
      const float4* KR4 = (const float4*)(B + 256);
      const float4* s4 = (const float4*)(lp_src + base);
      float4 a0 = s4[0], a1 = s4[1], a2 = s4[2], a3 = s4[3];
      lv[0]=a0.x; lv[1]=a0.y; lv[2]=a0.z; lv[3]=a0.w;
      lv[4]=a1.x; lv[5]=a1.y; lv[6]=a1.z; lv[7]=a1.w;
      lv[8]=a2.x; lv[9]=a2.y; lv[10]=a2.z; lv[11]=a2.w;
      lv[12]=a3.x; lv[13]=a3.y; lv[14]=a3.z; lv[15]=a3.w;
      float n2 = 0.f;
#pragma unroll
      for (int l = 0; l < 16; ++l) n2 += lv[l] * lv[l];
      float ri = rsqrtf(n2);
      float ls[16], L[16];
#pragma unroll
      for (int l = 0; l < 16; ++l) { ls[l] = lv[l] * ri; L[l] = ls[l] * ls[l]; }
      float dl[16];
#pragma unroll
      for (int l = 0; l < 16; ++l) dl[l] = 0.f;
#pragma unroll
      for (int k = 0; k < 16; ++k) {
        float Lk = L[k];
#pragma unroll
        for (int g = 0; g < 4; ++g) {
          float4 rr = RR4[k * 4 + g];
          dl[4*g+0] += Lk * rr.x; dl[4*g+1] += Lk * rr.y;
          dl[4*g+2] += Lk * rr.z; dl[4*g+3] += Lk * rr.w;
        }
      }
      const float4* q4 = (const float4*)(q + ((size_t)bh * S_ + j0 + t) * D_);
#pragma unroll
      for (int a4 = 0; a4 < 16; ++a4) {
        float4 qq = q4[a4];
#pragma unroll
        for (int c = 0; c < 4; ++c) {
          float qa = (c == 0) ? qq.x : (c == 1) ? qq.y : (c == 2) ? qq.z : qq.w;
          int a = a4 * 4 + c;
#pragma unroll
          for (int g = 0; g < 4; ++g) {
            float4 kr = KR4[a * 4 + g];
            dl[4*g+0] -= qa * kr.x; dl[4*g+1] -= qa * kr.y;
            dl[4*g+2] -= qa * kr.z; dl[4*g+3] -= qa * kr.w;
          }
        }
      }
      float dot = 0.f;
#pragma unroll
      for (int l = 0; l < 16; ++l) { dl[l] *= ls[l]; dot += ls[l] * dl[l]; }
#pragma unroll
      for (int l = 0; l < 16; ++l) lv[l] -= STEPSZ * (dl[l] - ls[l] * dot) * ri;
      float4* d4 = (float4*)(lp_dst + base);
      d4[0] = make_float4(lv[0], lv[1], lv[2], lv[3]);
      d4[1] = make_float4(lv[4], lv[5], lv[6], lv[7]);
      d4[2] = make_float4(lv[8], lv[9], lv[10], lv[11]);
      d4[3] = make_float4(lv[12], lv[13], lv[14], lv[15]);
      if (MODE == 2) return;
      __syncthreads();  // F consumed; B re-used for stage
    } else {
      const float4* s4 = (const float4*)(lp_src + base);
      float4 a0 = s4[0], a1 = s4[1], a2 = s4[2], a3 = s4[3];
      lv[0]=a0.x; lv[1]=a0.y; lv[2]=a0.z; lv[3]=a0.w;
      lv[4]=a1.x; lv[5]=a1.y; lv[6]=a1.z; lv[7]=a1.w;
      lv[8]=a2.x; lv[9]=a2.y; lv[10]=a2.z; lv[11]=a2.w;
      lv[12]=a3.x; lv[13]=a3.y; lv[14]=a3.z; lv[15]=a3.w;
      float4* d4 = (float4*)(lp_dst + base);
      d4[0] = a0; d4[1] = a1; d4[2] = a2; d4[3] = a3;
    }
    // stage L = lv^2 / |lv|^2
    {
      float m2 = 0.f;
#pragma unroll
      for (int l = 0; l < 16; ++l) m2 += lv[l] * lv[l];
      float r2 = 1.0f / m2;
      float4* st = (float4*)(B + t * 16);
      st[0] = make_float4(lv[0]*lv[0]*r2, lv[1]*lv[1]*r2, lv[2]*lv[2]*r2, lv[3]*lv[3]*r2);
      st[1] = make_float4(lv[4]*lv[4]*r2, lv[5]*lv[5]*r2, lv[6]*lv[6]*r2, lv[7]*lv[7]*r2);
      st[2] = make_float4(lv[8]*lv[8]*r2, lv[9]*lv[9]*r2, lv[10]*lv[10]*r2, lv[11]*lv[11]*r2);
      st[3] = make_float4(lv[12]*lv[12]*r2, lv[13]*lv[13]*r2, lv[14]*lv[14]*r2, lv[15]*lv[15]*r2);
    }
    __syncthreads();
    // reduce LL/LQ: thread (tc,trw) owns a-quad 4tc..4tc+3, rows trw mod 16
    float aQ[64], aL[16];
#pragma unroll
    for (int e = 0; e < 64; ++e) aQ[e] = 0.f;
#pragma unroll
    for (int l = 0; l < 16; ++l) aL[l] = 0.f;
    const float* qb = q + (size_t)bh * S_ * D_;
    for (int it = 0; it < 16; ++it) {
      int jl = trw + (it << 4);
      const float4* Lw = (const float4*)(B + jl * 16);
      float4 b0 = Lw[0], b1 = Lw[1], b2 = Lw[2], b3 = Lw[3];
      float Lv[16] = {b0.x,b0.y,b0.z,b0.w, b1.x,b1.y,b1.z,b1.w,
                      b2.x,b2.y,b2.z,b2.w, b3.x,b3.y,b3.z,b3.w};
      float Lc = B[jl * 16 + tc];
      float4 qq = *(const float4*)(qb + (size_t)(j0 + jl) * D_ + (tc << 2));
#pragma unroll
      for (int l = 0; l < 16; ++l) {
        aQ[l*4+0] += Lv[l] * qq.x; aQ[l*4+1] += Lv[l] * qq.y;
        aQ[l*4+2] += Lv[l] * qq.z; aQ[l*4+3] += Lv[l] * qq.w;
        aL[l] += Lv[l] * Lc;
      }
    }
#pragma unroll
    for (int e = 0; e < 64; ++e) {
      float v = aQ[e];
      v += __shfl_xor(v, 16); v += __shfl_xor(v, 32);
      aQ[e] = v;
    }
#pragma unroll
    for (int l = 0; l < 16; ++l) {
      float v = aL[l];
      v += __shfl_xor(v, 16); v += __shfl_xor(v, 32);
      aL[l] = v;
    }
    __syncthreads();  // stage reads done; B re-used for red
    if (lane < 16) {
      float* rg = B + w * 1600 + tc * 100;
      float4* rg4 = (float4*)rg;
#pragma unroll
      for (int l = 0; l < 16; ++l)
        rg4[l] = make_float4(aQ[l*4], aQ[l*4+1], aQ[l*4+2], aQ[l*4+3]);
#pragma unroll
      for (int l = 0; l < 16; ++l) rg[64 + l] = aL[l];
    }
    __syncthreads();
    float* pb = part + (size_t)(bh * 32 + bx) * PART_STRIDE;
#pragma unroll
    for (int r = 0; r < 4; ++r) {
      int o = t + r * 256;
      int tcL = o >> 6, sl = o & 63;
      int idx = tcL * 100 + sl;
      float s = B[idx] + B[idx + 1600] + B[idx + 3200] + B[idx + 4800];
      pb[((tcL << 2) + (sl & 3)) * 16 + (sl >> 2)] = s;  // LQ[l][a]
    }
    {
      int tcL = t >> 4, l = t & 15;
      int idx = tcL * 100 + 64 + l;
      float s = B[idx] + B[idx + 1600] + B[idx + 3200] + B[idx + 4800];
      pb[1024 + l * 16 + tcL] = s;  // LL
    }
  } else {
    // ========================= col side =========================
    const int i = j0 + t;
    const size_t cb = ((size_t)bh * S_ + i) * R_;  // transposed rp layout [i][16]
    float nv[16], rp2[16];
    if (MODE >= 1) {
      for (int e = t; e < 1328; e += 256) B[e] = (e < 1280) ? A[e] : A[1280 + e];
      __syncthreads();
      const float4* MLL4 = (const float4*)B;
      const float4* MLQ4 = (const float4*)(B + 256);
      const float* C1 = B + 1280;
      const float* C2 = B + 1296;
      const float* SRN = B + 1312;
      const float4* r4 = (const float4*)(rp_src + cb);
      float4 a0 = r4[0], a1 = r4[1], a2 = r4[2], a3 = r4[3];
      float rv[16] = {a0.x,a0.y,a0.z,a0.w, a1.x,a1.y,a1.z,a1.w,
                      a2.x,a2.y,a2.z,a2.w, a3.x,a3.y,a3.z,a3.w};
#pragma unroll
      for (int l = 0; l < 16; ++l) rp2[l] = rv[l] * rv[l];
      float s[16];
#pragma unroll
      for (int k = 0; k < 16; ++k) {
        float acc0 = 0.f;
#pragma unroll
        for (int g = 0; g < 4; ++g) {
          float4 m = MLL4[k * 4 + g];
          acc0 += m.x * rp2[4*g+0] + m.y * rp2[4*g+1] +
                  m.z * rp2[4*g+2] + m.w * rp2[4*g+3];
        }
        s[k] = acc0;
      }
      const float4* k4 = (const float4*)(key + ((size_t)bh * S_ + i) * D_);
#pragma unroll
      for (int a4 = 0; a4 < 16; ++a4) {
        float4 kk = k4[a4];
#pragma unroll
        for (int k = 0; k < 16; ++k) {
          float4 m = MLQ4[k * 16 + a4];
          s[k] -= m.x * kk.x + m.y * kk.y + m.z * kk.z + m.w * kk.w;
        }
      }
#pragma unroll
      for (int k = 0; k < 16; ++k) {
        float rs = rv[k] * SRN[k];
        float d2 = rs * s[k];
        nv[k] = C1[k] * rv[k] - C2[k] * d2;
        rp2[k] = nv[k] * nv[k];
      }
      float4* d4 = (float4*)(rp_dst + cb);
      d4[0] = make_float4(nv[0], nv[1], nv[2], nv[3]);
      d4[1] = make_float4(nv[4], nv[5], nv[6], nv[7]);
      d4[2] = make_float4(nv[8], nv[9], nv[10], nv[11]);
      d4[3] = make_float4(nv[12], nv[13], nv[14], nv[15]);
      __syncthreads();  // F consumed
    } else {
      const float* rsrc = rp_src + (size_t)bh * R_ * S_ + i;  // original [r][S]
#pragma unroll
      for (int k = 0; k < 16; ++k) {
        float x = rsrc[(size_t)k * S_];
        nv[k] = x;
        rp2[k] = x * x;
      }
      float4* d4 = (float4*)(rp_dst + cb);
      d4[0] = make_float4(nv[0], nv[1], nv[2], nv[3]);
      d4[1] = make_float4(nv[4], nv[5], nv[6], nv[7]);
      d4[2] = make_float4(nv[8], nv[9], nv[10], nv[11]);
      d4[3] = make_float4(nv[12], nv[13], nv[14], nv[15]);
    }
    // stage rp2
    {
      float4* st = (float4*)(B + t * 16);
      st[0] = make_float4(rp2[0], rp2[1], rp2[2], rp2[3]);
      st[1] = make_float4(rp2[4], rp2[5], rp2[6], rp2[7]);
      st[2] = make_float4(rp2[8], rp2[9], rp2[10], rp2[11]);
      st[3] = make_float4(rp2[12], rp2[13], rp2[14], rp2[15]);
    }
    __syncthreads();
    float aQ[64], aR[16], aN[16];
#pragma unroll
    for (int e = 0; e < 64; ++e) aQ[e] = 0.f;
#pragma unroll
    for (int l = 0; l < 16; ++l) { aR[l] = 0.f; aN[l] = 0.f; }
    const float* sb = ((MODE == 2) ? vv : key) + (size_t)bh * S_ * D_;
    for (int it = 0; it < 16; ++it) {
      int jl = trw + (it << 4);
      const float4* Rw = (const float4*)(B + jl * 16);
      float4 b0 = Rw[0], b1 = Rw[1], b2 = Rw[2], b3 = Rw[3];
      float rw[16] = {b0.x,b0.y,b0.z,b0.w, b1.x,b1.y,b1.z,b1.w,
                      b2.x,b2.y,b2.z,b2.w, b3.x,b3.y,b3.z,b3.w};
      float rc = (MODE < 2) ? B[jl * 16 + tc] : 0.f;
      float4 kk = *(const float4*)(sb + (size_t)(j0 + jl) * D_ + (tc << 2));
#pragma unroll
      for (int l = 0; l < 16; ++l) {
        aQ[l*4+0] += rw[l] * kk.x; aQ[l*4+1] += rw[l] * kk.y;
        aQ[l*4+2] += rw[l] * kk.z; aQ[l*4+3] += rw[l] * kk.w;
        if (MODE < 2) aR[l] += rw[l] * rc;
        aN[l] += rw[l];
      }
    }
#pragma unroll
    for (int e = 0; e < 64; ++e) {
      float v = aQ[e];
      v += __shfl_xor(v, 16); v += __shfl_xor(v, 32);
      aQ[e] = v;
    }
#pragma unroll
    for (int l = 0; l < 16; ++l) {
      float v = aN[l];
      v += __shfl_xor(v, 16); v += __shfl_xor(v, 32);
      aN[l] = v;
      if (MODE < 2) {
        float u = aR[l];
        u += __shfl_xor(u, 16); u += __shfl_xor(u, 32);
        aR[l] = u;
      }
    }
    __syncthreads();
    if (lane < 16) {
      float* rg = B + w * 1600 + tc * 100;
      float4* rg4 = (float4*)rg;
#pragma unroll
      for (int l = 0; l < 16; ++l)
        rg4[l] = make_float4(aQ[l*4], aQ[l*4+1], aQ[l*4+2], aQ[l*4+3]);
      if (MODE < 2) {
#pragma unroll
        for (int l = 0; l < 16; ++l) rg[64 + l] = aR[l];
      }
    }
    if (lane == 0) {
#pragma unroll
      for (int l = 0; l < 16; ++l) B[w * 1600 + 80 + l] = aN[l];
    }
    __syncthreads();
    if (MODE < 2) {
      float* pb = part + (size_t)(bh * 32 + bx) * PART_STRIDE + 1280;
#pragma unroll
      for (int r = 0; r < 4; ++r) {
        int o = t + r * 256;
        int tcL = o >> 6, sl = o & 63;
        int idx = tcL * 100 + sl;
        float s = B[idx] + B[idx + 1600] + B[idx + 3200] + B[idx + 4800];
        pb[((tcL << 2) + (sl & 3)) * 16 + (sl >> 2)] = s;  // KR[l][a]
      }
      {
        int tcL = t >> 4, l = t & 15;
        int idx = tcL * 100 + 64 + l;
        float s = B[idx] + B[idx + 1600] + B[idx + 3200] + B[idx + 4800];
        pb[1024 + l * 16 + tcL] = s;  // RR
      }
      if (t < 16) {
        int idx = 80 + t;
        pb[1280 + t] = B[idx] + B[idx + 1600] + B[idx + 3200] + B[idx + 4800];  // N
      }
    } else {
      float* pb2 = part2 + (size_t)(bh * 32 + bx) * PART2_STRIDE;
#pragma unroll
      for (int r = 0; r < 4; ++r) {
        int o = t + r * 256;
        int tcL = o >> 6, sl = o & 63;
        int idx = tcL * 100 + sl;
        float s = B[idx] + B[idx + 1600] + B[idx + 3200] + B[idx + 4800];
        pb2[((tcL << 2) + (sl & 3)) * 16 + (sl >> 2)] = s;  // RV[l][d]
      }
      if (t < 16) {
        int idx = 80 + t;
        pb2[1024 + t] = B[idx] + B[idx + 1600] + B[idx + 3200] + B[idx + 4800];  // N
      }
    }
  }
}

// ---------------------------------------------------------------------------
// kB: one block per bh. Sum 32 partials -> derived matrices + analytic PJ, c1/c2.
// ---------------------------------------------------------------------------
__global__ void __launch_bounds__(256) kB(const float* __restrict__ part,
                                          float* __restrict__ accF) {
  const int bh = blockIdx.x, t = threadIdx.x;
  __shared__ float raw[PART_STRIDE];
  __shared__ float inn[16], srn[16];
  const float* p0 = part + (size_t)bh * 32 * PART_STRIDE;
  for (int v = t; v < PART_STRIDE; v += 256) {
    float s = 0.f;
    const float* p = p0 + v;
#pragma unroll 8
    for (int b = 0; b < 32; ++b) s += p[(size_t)b * PART_STRIDE];
    raw[v] = s;
  }
  __syncthreads();
  if (t < 16) {
    float N = raw[2560 + t];
    inn[t] = 1.0f / N;
    srn[t] = rsqrtf(N);
  }
  __syncthreads();
  float* out = accF + (size_t)bh * ACCF_STRIDE;
  out[t] = raw[1024 + t] * CC * inn[t & 15];                       // MLL[k][l]
  out[1280 + t] = raw[2304 + t] * CC * inn[t >> 4] * inn[t & 15];  // RRS[k][l]
#pragma unroll
  for (int r = 0; r < 4; ++r) {  // MLQ[k*64+a] = LQ[k][a]*CC, LQ at raw[a*16+k]
    int e = t + r * 256;
    out[256 + e] = raw[((e & 63) << 4) + (e >> 6)] * CC;
  }
#pragma unroll
  for (int r = 0; r < 4; ++r) {  // KRT[a*16+l] = KR[l][a]*CC*inn[l]
    int e = t + r * 256;
    out[1536 + e] = raw[1280 + e] * CC * inn[e & 15];
  }
  if (t < 16) {
    int k = t;
    float s = 0.f;
#pragma unroll
    for (int l = 0; l < 16; ++l)
      s += raw[1024 + k * 16 + l] * CC * inn[l] * raw[2304 + k * 16 + l];
#pragma unroll
    for (int a = 0; a < 64; ++a)
      s -= raw[a * 16 + k] * CC * raw[1280 + a * 16 + k];
    float PJ = inn[k] * s;
    out[2560 + t] = 1.0f + STEPSZ * PJ * inn[t];  // c1
    out[2576 + t] = STEPSZ * srn[t];              // c2
    out[2592 + t] = srn[t];
    out[2608 + t] = inn[t];
  }
}

// ---------------------------------------------------------------------------
// kBF: sum RV partials, scale by 1/N -> RVs[k][d] (k*64+d layout)
// ---------------------------------------------------------------------------
__global__ void __launch_bounds__(256) kBF(const float* __restrict__ part2,
                                           float* __restrict__ RVs) {
  const int bh = blockIdx.x, t = threadIdx.x;
  __shared__ float raw[PART2_STRIDE];
  __shared__ float inn[16];
  const float* p0 = part2 + (size_t)bh * 32 * PART2_STRIDE;
  for (int v = t; v < PART2_STRIDE; v += 256) {
    float s = 0.f;
    const float* p = p0 + v;
#pragma unroll 8
    for (int b = 0; b < 32; ++b) s += p[(size_t)b * PART2_STRIDE];
    raw[v] = s;
  }
  __syncthreads();
  if (t < 16) inn[t] = 1.0f / raw[1024 + t];
  __syncthreads();
#pragma unroll
  for (int r = 0; r < 4; ++r) {
    int e = t + r * 256;  // e = k*64+d; RV at raw[d*16+k]
    RVs[(size_t)bh * 1024 + e] = raw[((e & 63) << 4) + (e >> 6)] * inn[e >> 6];
  }
}

// out[j][d] = sum_k unit(lp_j)^2[k] * RVs[k][d]
__global__ void __launch_bounds__(256) kOut(const float* __restrict__ lp,
                                            const float* __restrict__ RVs,
                                            float* __restrict__ out) {
  const int bh = blockIdx.y, t = threadIdx.x;
  __shared__ float rvs[1024];
#pragma unroll
  for (int r = 0; r < 4; ++r) rvs[t + r * 256] = RVs[(size_t)bh * 1024 + t + r * 256];
  __syncthreads();
  const int j = blockIdx.x * 256 + t;
  size_t base = ((size_t)bh * S_ + j) * R_;
  const float4* lp4 = (const float4*)(lp + base);
  float4 a0 = lp4[0], a1 = lp4[1], a2 = lp4[2], a3 = lp4[3];
  float lv[16] = {a0.x,a0.y,a0.z,a0.w, a1.x,a1.y,a1.z,a1.w,
                  a2.x,a2.y,a2.z,a2.w, a3.x,a3.y,a3.z,a3.w};
  float n2 = 0.f;
#pragma unroll
  for (int l = 0; l < 16; ++l) n2 += lv[l] * lv[l];
  float r2 = 1.0f / n2;
  float L[16];
#pragma unroll
  for (int l = 0; l < 16; ++l) L[l] = lv[l] * lv[l] * r2;
  float o[64];
#pragma unroll
  for (int d = 0; d < 64; ++d) o[d] = 0.f;
  const float4* rv4 = (const float4*)rvs;
#pragma unroll
  for (int k = 0; k < 16; ++k) {
    float Lk = L[k];
#pragma unroll
    for (int d4 = 0; d4 < 16; ++d4) {
      float4 r = rv4[k * 16 + d4];
      o[4*d4+0] += Lk * r.x; o[4*d4+1] += Lk * r.y;
      o[4*d4+2] += Lk * r.z; o[4*d4+3] += Lk * r.w;
    }
  }
  float4* o4 = (float4*)(out + ((size_t)bh * S_ + j) * D_);
#pragma unroll
  for (int d4 = 0; d4 < 16; ++d4)
    o4[d4] = make_float4(o[4*d4+0], o[4*d4+1], o[4*d4+2], o[4*d4+3]);
}

extern "C" void kernel_launch(void* const* d_in, const int* in_sizes, int n_in,
                              void* d_out, int out_size, void* d_ws, size_t ws_size,
                              hipStream_t stream) {
  (void)in_sizes; (void)n_in; (void)out_size; (void)ws_size;
  const float* q = (const float*)d_in[0];
  const float* key = (const float*)d_in[1];
  const float* v = (const float*)d_in[2];
  const float* lp0 = (const float*)d_in[3];
  const float* rp0 = (const float*)d_in[4];
  float* out = (float*)d_out;
  float* ws = (float*)d_ws;

  float* lp = ws;                  // 3,145,728
  float* rp = lp + LP_N;           // 3,145,728 (transposed [i][16])
  float* part = rp + LP_N;         // 1,978,368
  float* accF = part + PART_N;     // 62,976
  float* part2 = accF + ACCF_N;    // 798,720
  float* RVs = part2 + PART2_N;    // 24,576
  // total 9,156,096 floats = 36.6 MB

  dim3 blk(256);
  dim3 gS(32, BH_, 2);
  // init: copy lp0/rp0 into internal layout + initial partial reductions
  kStep<0><<<gS, blk, 0, stream>>>(accF, q, key, v, lp0, rp0, lp, rp, part, part2);
  for (int s = 0; s < 10; ++s) {
    kB<<<dim3(BH_), blk, 0, stream>>>(part, accF);
    if (s < 9)
      kStep<1><<<gS, blk, 0, stream>>>(accF, q, key, v, lp, rp, lp, rp, part, part2);
    else
      kStep<2><<<gS, blk, 0, stream>>>(accF, q, key, v, lp, rp, lp, rp, part, part2);
  }
  kBF<<<dim3(BH_), blk, 0, stream>>>(part2, RVs);
  kOut<<<dim3(32, BH_), blk, 0, stream>>>(lp, RVs, out);
}